// Round 2
// baseline (3695.206 us; speedup 1.0000x reference)
//
#include <hip/hip_runtime.h>

// ---------------------------------------------------------------------------
// Problem constants
// B=8, N=1024, CIN=2048, HID=1024, HC=64, LV=512, NH_SSD=16, HD=128, DS=64,
// DCONV=4. Encoder rows = 8*512 = 4096. Decoder collapses to 1 row/batch
// (all masked positions share mask_token -> identical dx/Q/attention output).
// ---------------------------------------------------------------------------

// ---------------------------------------------------------------------------
// Reduction helpers (blockDim 256)
// ---------------------------------------------------------------------------
__device__ __forceinline__ float block_sum256(float v) {
    #pragma unroll
    for (int o = 32; o > 0; o >>= 1) v += __shfl_xor(v, o, 64);
    __shared__ float sm[4];
    int w = threadIdx.x >> 6;
    __syncthreads();
    if ((threadIdx.x & 63) == 0) sm[w] = v;
    __syncthreads();
    return sm[0] + sm[1] + sm[2] + sm[3];
}

__device__ __forceinline__ float block_max256(float v) {
    #pragma unroll
    for (int o = 32; o > 0; o >>= 1) v = fmaxf(v, __shfl_xor(v, o, 64));
    __shared__ float smx[4];
    int w = threadIdx.x >> 6;
    __syncthreads();
    if ((threadIdx.x & 63) == 0) smx[w] = v;
    __syncthreads();
    return fmaxf(fmaxf(smx[0], smx[1]), fmaxf(smx[2], smx[3]));
}

// ---------------------------------------------------------------------------
// Tiled f32 GEMM: C[m,n] = alpha * sum_k A[m,k] * B'[n,k]  (+bias[n]) (+res)
//   BIsKN=false: B is (N,K) row-major (NT, weight layout)
//   BIsKN=true : B is (K,N) row-major (NN, e.g. P@V)
// Batched via blockIdx.z: z -> (bb=z/nh, hh=z%nh) pointer offsets.
// M multiple of 128, K multiple of 32 (true for all calls). N may be ragged.
// ---------------------------------------------------------------------------
template<bool BIsKN>
__global__ __launch_bounds__(256) void gemm_k(
    int M, int N, int K,
    const float* __restrict__ A, int lda, long long sAb, long long sAh,
    const float* __restrict__ B, int ldb, long long sBb, long long sBh,
    float* __restrict__ C, int ldc, long long sCb, long long sCh,
    const float* __restrict__ bias,
    const float* __restrict__ res, int ldr,
    float alpha, int nh)
{
    __shared__ float As[32][132];
    __shared__ float Bs[32][132];
    const int z  = blockIdx.z;
    const int bb = z / nh, hh = z - bb * nh;
    A += bb * sAb + hh * sAh;
    B += bb * sBb + hh * sBh;
    C += bb * sCb + hh * sCh;
    const int n0 = blockIdx.x * 128;
    const int m0 = blockIdx.y * 128;
    const int t  = threadIdx.x;
    const int tx = t & 15, ty = t >> 4;

    float acc[4][16];
    #pragma unroll
    for (int a = 0; a < 4; ++a)
        #pragma unroll
        for (int q = 0; q < 16; ++q) acc[a][q] = 0.f;

    const int ka  = (t & 7) << 2;   // k offset for NT-style loads
    const int ra  = t >> 3;         // row 0..31
    const int nb2 = (t & 31) << 2;  // col offset for KN loads
    const int kb2 = t >> 5;         // k row 0..7

    for (int k0 = 0; k0 < K; k0 += 32) {
        __syncthreads();
        #pragma unroll
        for (int i = 0; i < 4; ++i) {
            int row = m0 + ra + i * 32;
            float4 v = *(const float4*)(A + (long long)row * lda + (k0 + ka));
            As[ka + 0][ra + i * 32] = v.x;
            As[ka + 1][ra + i * 32] = v.y;
            As[ka + 2][ra + i * 32] = v.z;
            As[ka + 3][ra + i * 32] = v.w;
        }
        if (!BIsKN) {
            #pragma unroll
            for (int i = 0; i < 4; ++i) {
                int row = n0 + ra + i * 32;
                float4 v = make_float4(0.f, 0.f, 0.f, 0.f);
                if (row < N) v = *(const float4*)(B + (long long)row * ldb + (k0 + ka));
                Bs[ka + 0][ra + i * 32] = v.x;
                Bs[ka + 1][ra + i * 32] = v.y;
                Bs[ka + 2][ra + i * 32] = v.z;
                Bs[ka + 3][ra + i * 32] = v.w;
            }
        } else {
            #pragma unroll
            for (int i = 0; i < 4; ++i) {
                int kr  = kb2 + i * 8;
                int col = n0 + nb2;
                float4 v = make_float4(0.f, 0.f, 0.f, 0.f);
                if (col < N) v = *(const float4*)(B + (long long)(k0 + kr) * ldb + col);
                *(float4*)&Bs[kr][nb2] = v;
            }
        }
        __syncthreads();
        #pragma unroll
        for (int kk = 0; kk < 32; ++kk) {
            float a[8], bm[8];
            *(float4*)&a[0]  = *(const float4*)&As[kk][ty * 4];
            *(float4*)&a[4]  = *(const float4*)&As[kk][64 + ty * 4];
            *(float4*)&bm[0] = *(const float4*)&Bs[kk][tx * 4];
            *(float4*)&bm[4] = *(const float4*)&Bs[kk][64 + tx * 4];
            #pragma unroll
            for (int ri = 0; ri < 2; ++ri)
                #pragma unroll
                for (int ci = 0; ci < 2; ++ci)
                    #pragma unroll
                    for (int i = 0; i < 4; ++i)
                        #pragma unroll
                        for (int j = 0; j < 4; ++j)
                            acc[ri * 2 + ci][i * 4 + j] =
                                fmaf(a[ri * 4 + i], bm[ci * 4 + j], acc[ri * 2 + ci][i * 4 + j]);
        }
    }

    #pragma unroll
    for (int ri = 0; ri < 2; ++ri)
        #pragma unroll
        for (int ci = 0; ci < 2; ++ci) {
            int colb = n0 + ci * 64 + tx * 4;
            if (colb >= N) continue;
            float4 bv = make_float4(0.f, 0.f, 0.f, 0.f);
            if (bias) bv = *(const float4*)(bias + colb);
            #pragma unroll
            for (int i = 0; i < 4; ++i) {
                int row = m0 + ri * 64 + ty * 4 + i;
                float4 o;
                o.x = alpha * acc[ri * 2 + ci][i * 4 + 0] + bv.x;
                o.y = alpha * acc[ri * 2 + ci][i * 4 + 1] + bv.y;
                o.z = alpha * acc[ri * 2 + ci][i * 4 + 2] + bv.z;
                o.w = alpha * acc[ri * 2 + ci][i * 4 + 3] + bv.w;
                if (res) {
                    float4 rv = *(const float4*)(res + (long long)row * ldr + colb);
                    o.x += rv.x; o.y += rv.y; o.z += rv.z; o.w += rv.w;
                }
                *(float4*)(C + (long long)row * ldc + colb) = o;
            }
        }
}

// ---------------------------------------------------------------------------
// LayerNorm over `width` (multiple of 256). Row r of input lives at
// in + (r/rows_per_b)*in_bstride + (r%rows_per_b)*width. Output contiguous.
// ---------------------------------------------------------------------------
__global__ __launch_bounds__(256) void layernorm_k(
    const float* __restrict__ in, float* __restrict__ out,
    const float* __restrict__ w, const float* __restrict__ b,
    int width, int rows_per_b, long long in_bstride)
{
    long long r = blockIdx.x;
    const float* x = in + (r / rows_per_b) * in_bstride + (r % rows_per_b) * (long long)width;
    int t = threadIdx.x;
    float s = 0.f;
    for (int c = t; c < width; c += 256) s += x[c];
    s = block_sum256(s);
    float m = s / (float)width;
    float vs = 0.f;
    for (int c = t; c < width; c += 256) { float d = x[c] - m; vs += d * d; }
    vs = block_sum256(vs);
    float rs = 1.f / sqrtf(vs / (float)width + 1e-5f);
    float* o = out + r * (long long)width;
    for (int c = t; c < width; c += 256) o[c] = (x[c] - m) * rs * w[c] + b[c];
}

__global__ __launch_bounds__(256) void rmsnorm_k(
    const float* __restrict__ in, float* __restrict__ out,
    const float* __restrict__ w, int width)
{
    long long r = blockIdx.x;
    const float* x = in + r * (long long)width;
    int t = threadIdx.x;
    float s = 0.f;
    for (int c = t; c < width; c += 256) { float v = x[c]; s += v * v; }
    s = block_sum256(s);
    float rs = 1.f / sqrtf(s / (float)width + 1e-5f);
    float* o = out + r * (long long)width;
    for (int c = t; c < width; c += 256) o[c] = x[c] * rs * w[c];
}

// In-place row softmax, width 512 (encoder attention).
__global__ __launch_bounds__(256) void softmax_k(float* __restrict__ S)
{
    long long r = blockIdx.x;
    float* x = S + r * 512;
    int t = threadIdx.x;
    float v0 = x[t], v1 = x[t + 256];
    float mx = block_max256(fmaxf(v0, v1));
    v0 = expf(v0 - mx); v1 = expf(v1 - mx);
    float sum = block_sum256(v0 + v1);
    float inv = 1.f / sum;
    x[t] = v0 * inv; x[t + 256] = v1 * inv;
}

// Depthwise-grouped causal conv: XC[b,t,o] = sum_{i<2,k<4} XS[b,t+k-3,2*(o/2)+i]*W[o,i,k]
__global__ __launch_bounds__(256) void conv_k(
    const float* __restrict__ XS, const float* __restrict__ W, float* __restrict__ XC)
{
    int idx = blockIdx.x * 256 + threadIdx.x;           // 8*512*2048 = 2^23
    int o = idx & 2047;
    int tt = (idx >> 11) & 511;
    int b = idx >> 20;
    int g2 = (o >> 1) << 1;
    const float* Wo = W + o * 8;
    float acc = 0.f;
    #pragma unroll
    for (int k = 0; k < 4; ++k) {
        int ts = tt + k - 3;
        if (ts >= 0) {
            const float* xr = XS + ((long long)(b * 512 + ts)) * 2048;
            acc = fmaf(Wo[k], xr[g2], acc);
            acc = fmaf(Wo[4 + k], xr[g2 + 1], acc);
        }
    }
    XC[idx] = acc;
}

// dt = softplus(dtBC[:, :16] + dt_bias)
__global__ __launch_bounds__(256) void dt_k(
    const float* __restrict__ dtBC, const float* __restrict__ dt_bias, float* __restrict__ DT)
{
    int idx = blockIdx.x * 256 + threadIdx.x;  // 4096*16 = 65536
    int r = idx >> 4, h = idx & 15;
    float xv = dtBC[r * 144 + h] + dt_bias[h];
    DT[idx] = (xv > 20.f) ? xv : log1pf(expf(xv));
}

// cumA[b,h,l] = cumsum_l( -exp(A_log[h]) * dt[b,l,h] ), one wave per (b,h)
__global__ __launch_bounds__(64) void cuma_k(
    const float* __restrict__ DT, const float* __restrict__ A_log, float* __restrict__ CUMA)
{
    int h = blockIdx.x, b = blockIdx.y;
    int ln = threadIdx.x;
    float Ah = -expf(A_log[h]);
    float v[8];
    float run = 0.f;
    #pragma unroll
    for (int i = 0; i < 8; ++i) {
        run += Ah * DT[((b * 512) + (ln * 8 + i)) * 16 + h];
        v[i] = run;
    }
    float tot = run;
    float sc = tot;
    #pragma unroll
    for (int o = 1; o <= 32; o <<= 1) {
        float u = __shfl_up(sc, o, 64);
        if (ln >= o) sc += u;
    }
    float excl = sc - tot;
    #pragma unroll
    for (int i = 0; i < 8; ++i)
        CUMA[(b * 16 + h) * 512 + ln * 8 + i] = excl + v[i];
}

// SSD intra-chunk apply + D-skip + silu(z) gate. YS may alias Z (in-place):
// each element read exactly once by its own writer thread.
// grid (32 l-tiles, 16 heads, 8 batch), block 256 = 128 p-lanes x 2 l-groups
__global__ __launch_bounds__(256) void ssd_apply_k(
    const float* __restrict__ G, const float* __restrict__ CUMA,
    const float* __restrict__ DT, const float* __restrict__ XC,
    const float* __restrict__ Z, const float* __restrict__ Dv,
    float* __restrict__ YS)
{
    int lt = blockIdx.x, h = blockIdx.y, b = blockIdx.z;
    int t = threadIdx.x;
    int p = t & 127, lg = t >> 7;
    int li = t >> 4, si = t & 15;
    __shared__ float XCs[16][128];
    __shared__ float Ws[16][16];
    float acc[8];
    #pragma unroll
    for (int r = 0; r < 8; ++r) acc[r] = 0.f;

    int lglob = lt * 16 + li;
    float cAl = CUMA[(b * 16 + h) * 512 + lglob];

    for (int st = 0; st <= lt; ++st) {
        __syncthreads();
        #pragma unroll
        for (int j = 0; j < 8; ++j) {
            int idx = t + j * 256;
            int sr = idx >> 7, sc = idx & 127;
            XCs[sr][sc] = XC[((long long)(b * 512 + st * 16 + sr)) * 2048 + h * 128 + sc];
        }
        int sglob = st * 16 + si;
        float wv = 0.f;
        if (sglob <= lglob) {
            float cAs = CUMA[(b * 16 + h) * 512 + sglob];
            wv = G[((long long)(b * 512 + lglob)) * 512 + sglob] * expf(cAl - cAs)
                 * DT[(b * 512 + sglob) * 16 + h];
        }
        Ws[li][si] = wv;
        __syncthreads();
        #pragma unroll
        for (int ss = 0; ss < 16; ++ss) {
            float xv = XCs[ss][p];
            #pragma unroll
            for (int r = 0; r < 8; ++r)
                acc[r] = fmaf(Ws[lg + r * 2][ss], xv, acc[r]);
        }
    }
    float Dh = Dv[h];
    #pragma unroll
    for (int r = 0; r < 8; ++r) {
        int l = lt * 16 + lg + r * 2;
        long long base = ((long long)(b * 512 + l)) * 2048 + h * 128 + p;
        float zz = Z[base];
        float sil = zz / (1.f + expf(-zz));
        YS[base] = (acc[r] + XC[base] * Dh) * sil;
    }
}

// hc = LayerNorm64(G1) -> quantize to {-1,+1}
__global__ __launch_bounds__(64) void hc_quant_k(
    const float* __restrict__ G1, const float* __restrict__ w,
    const float* __restrict__ b, float* __restrict__ HCQ)
{
    int r = blockIdx.x, ln = threadIdx.x;
    float v = G1[r * 64 + ln];
    float s = v;
    #pragma unroll
    for (int o = 32; o > 0; o >>= 1) s += __shfl_xor(s, o, 64);
    float m = s * (1.f / 64.f);
    float d = v - m;
    float vs = d * d;
    #pragma unroll
    for (int o = 32; o > 0; o >>= 1) vs += __shfl_xor(vs, o, 64);
    vs *= (1.f / 64.f);
    float hc = d * (1.f / sqrtf(vs + 1e-5f)) * w[ln] + b[ln];
    HCQ[r * 64 + ln] = (hc > 0.f) ? 1.f : -1.f;
}

// dxm[c] = sum_j mask_token[j] * e2d_W[c,j]   (1024 threads)
__global__ __launch_bounds__(256) void dxm_k(
    const float* __restrict__ mtok, const float* __restrict__ e2d, float* __restrict__ dxm)
{
    int c = blockIdx.x * 256 + threadIdx.x;
    float acc = 0.f;
    #pragma unroll
    for (int j = 0; j < 64; ++j) acc = fmaf(mtok[j], e2d[c * 64 + j], acc);
    dxm[c] = acc;
}

// qm/km/vm[c] = sum_j lnm[j] * bW{q,k,v}[c,j]   (3072 threads)
__global__ __launch_bounds__(256) void projm_k(
    const float* __restrict__ lnm,
    const float* __restrict__ bWq, const float* __restrict__ bWk, const float* __restrict__ bWv,
    float* __restrict__ qm, float* __restrict__ km, float* __restrict__ vm)
{
    int idx = blockIdx.x * 256 + threadIdx.x;
    int sel = idx >> 10, c = idx & 1023;
    const float* W = (sel == 0) ? bWq : (sel == 1) ? bWk : bWv;
    float* O = (sel == 0) ? qm : (sel == 1) ? km : vm;
    const float* wr = W + (long long)c * 1024;
    float acc = 0.f;
    for (int j = 0; j < 1024; j += 4) {
        float4 a = *(const float4*)(lnm + j);
        float4 w4 = *(const float4*)(wr + j);
        acc = fmaf(a.x, w4.x, fmaf(a.y, w4.y, fmaf(a.z, w4.z, fmaf(a.w, w4.w, acc))));
    }
    O[c] = acc;
}

// Decoder attention, collapsed: one query (qm) per (batch,head); keys = 512
// visible rows + masked key with multiplicity 512. grid (4 heads, 8 batches).
__global__ __launch_bounds__(256) void dec_attn_k(
    const float* __restrict__ Kv, const float* __restrict__ Vv,
    const float* __restrict__ qm, const float* __restrict__ km,
    const float* __restrict__ vm, float* __restrict__ OBm)
{
    int h = blockIdx.x, b = blockIdx.y;
    int t = threadIdx.x;
    __shared__ __align__(16) float qs[256];
    __shared__ __align__(16) float ps[512];
    qs[t] = qm[h * 256 + t];
    __syncthreads();
    float s[2];
    #pragma unroll
    for (int i = 0; i < 2; ++i) {
        int r = t + i * 256;
        const float* kr = Kv + ((long long)(b * 512 + r)) * 1024 + h * 256;
        float acc = 0.f;
        for (int c = 0; c < 256; c += 4) {
            float4 k4 = *(const float4*)(kr + c);
            float4 q4 = *(const float4*)(qs + c);
            acc = fmaf(k4.x, q4.x, fmaf(k4.y, q4.y, fmaf(k4.z, q4.z, fmaf(k4.w, q4.w, acc))));
        }
        s[i] = acc * (1.f / 16.f);
    }
    float accm = 0.f;
    for (int c = 0; c < 256; c += 4) {
        float4 k4 = *(const float4*)(km + h * 256 + c);
        float4 q4 = *(const float4*)(qs + c);
        accm = fmaf(k4.x, q4.x, fmaf(k4.y, q4.y, fmaf(k4.z, q4.z, fmaf(k4.w, q4.w, accm))));
    }
    float smv = accm * (1.f / 16.f);
    float mx = block_max256(fmaxf(fmaxf(s[0], s[1]), smv));
    float p0 = expf(s[0] - mx), p1 = expf(s[1] - mx);
    ps[t] = p0; ps[t + 256] = p1;
    float pm = expf(smv - mx) * 512.f;
    float sum = block_sum256(p0 + p1) + pm;
    float inv = 1.f / sum;
    __syncthreads();
    float o = pm * vm[h * 256 + t];
    const float* vcol = Vv + (long long)b * 512 * 1024 + h * 256 + t;
    for (int j = 0; j < 512; ++j)
        o = fmaf(ps[j], vcol[(long long)j * 1024], o);
    OBm[b * 1024 + h * 256 + t] = o * inv;
}

// ydm[b,c] = sum_j OBm[b,j]*bWo[c,j] + bWo_b[c] + dxm[c]   (8192 threads)
__global__ __launch_bounds__(256) void ydm_k(
    const float* __restrict__ OBm, const float* __restrict__ bWo,
    const float* __restrict__ bWo_b, const float* __restrict__ dxm,
    float* __restrict__ ydm)
{
    int idx = blockIdx.x * 256 + threadIdx.x;
    int b = idx >> 10, c = idx & 1023;
    const float* ar = OBm + b * 1024;
    const float* wr = bWo + (long long)c * 1024;
    float acc = 0.f;
    for (int j = 0; j < 1024; j += 4) {
        float4 a = *(const float4*)(ar + j);
        float4 w4 = *(const float4*)(wr + j);
        acc = fmaf(a.x, w4.x, fmaf(a.y, w4.y, fmaf(a.z, w4.z, fmaf(a.w, w4.w, acc))));
    }
    ydm[idx] = acc + bWo_b[c] + dxm[c];
}

// outm[b,c] = sum_j ydm[b,j]*dout_W[c,j] + dout_b[c]   (16384 threads)
__global__ __launch_bounds__(256) void outm_k(
    const float* __restrict__ ydm, const float* __restrict__ dout_W,
    const float* __restrict__ dout_b, float* __restrict__ outm)
{
    int idx = blockIdx.x * 256 + threadIdx.x;
    int b = idx >> 11, c = idx & 2047;
    const float* ar = ydm + b * 1024;
    const float* wr = dout_W + (long long)c * 1024;
    float acc = 0.f;
    for (int j = 0; j < 1024; j += 4) {
        float4 a = *(const float4*)(ar + j);
        float4 w4 = *(const float4*)(wr + j);
        acc = fmaf(a.x, w4.x, fmaf(a.y, w4.y, fmaf(a.z, w4.z, fmaf(a.w, w4.w, acc))));
    }
    outm[idx] = acc + dout_b[c];
}

// out[b,l,:] = outm[b,:] for all l in [0,512)   (float4 granularity)
__global__ __launch_bounds__(256) void bcast_k(
    const float* __restrict__ outm, float* __restrict__ out)
{
    int idx = blockIdx.x * 256 + threadIdx.x;   // 8*512*512 float4s
    int c4 = idx & 511;
    int b = idx >> 18;
    ((float4*)out)[idx] = ((const float4*)outm)[b * 512 + c4];
}

// ---------------------------------------------------------------------------
// Host-side launcher
// ---------------------------------------------------------------------------
static inline void gemm(hipStream_t s, bool bkn, int M, int N, int K,
                        const float* A, int lda, long long sAb, long long sAh,
                        const float* B, int ldb, long long sBb, long long sBh,
                        float* C, int ldc, long long sCb, long long sCh,
                        const float* bias, const float* res, int ldr,
                        float alpha, int nh, int batches)
{
    dim3 g((N + 127) / 128, (M + 127) / 128, batches);
    if (bkn)
        gemm_k<true><<<g, 256, 0, s>>>(M, N, K, A, lda, sAb, sAh, B, ldb, sBb, sBh,
                                       C, ldc, sCb, sCh, bias, res, ldr, alpha, nh);
    else
        gemm_k<false><<<g, 256, 0, s>>>(M, N, K, A, lda, sAb, sAh, B, ldb, sBb, sBh,
                                        C, ldc, sCb, sCh, bias, res, ldr, alpha, nh);
}

extern "C" void kernel_launch(void* const* d_in, const int* in_sizes, int n_in,
                              void* d_out, int out_size, void* d_ws, size_t ws_size,
                              hipStream_t stream)
{
    const float* x       = (const float*)d_in[0];
    const float* ln0_w   = (const float*)d_in[1];
    const float* ln0_b   = (const float*)d_in[2];
    const float* in_W    = (const float*)d_in[3];
    const float* rms_w   = (const float*)d_in[4];
    const float* exp_W   = (const float*)d_in[5];
    const float* conv_W  = (const float*)d_in[6];
    const float* xproj_W = (const float*)d_in[7];
    const float* dt_bias = (const float*)d_in[8];
    const float* A_log   = (const float*)d_in[9];
    const float* Dv      = (const float*)d_in[10];
    const float* outp_W  = (const float*)d_in[11];
    const float* outp_b  = (const float*)d_in[12];
    const float* n1_w    = (const float*)d_in[13];
    const float* n1_b    = (const float*)d_in[14];
    const float* aWq     = (const float*)d_in[15];
    const float* aWk     = (const float*)d_in[16];
    const float* aWv     = (const float*)d_in[17];
    const float* aWo     = (const float*)d_in[18];
    const float* aWo_b   = (const float*)d_in[19];
    const float* h_W     = (const float*)d_in[20];
    const float* h_b     = (const float*)d_in[21];
    const float* h_lnw   = (const float*)d_in[22];
    const float* h_lnb   = (const float*)d_in[23];
    const float* mtok    = (const float*)d_in[24];
    const float* e2d_W   = (const float*)d_in[25];
    const float* dn_w    = (const float*)d_in[26];
    const float* dn_b    = (const float*)d_in[27];
    const float* bWq     = (const float*)d_in[28];
    const float* bWk     = (const float*)d_in[29];
    const float* bWv     = (const float*)d_in[30];
    const float* bWo     = (const float*)d_in[31];
    const float* bWo_b   = (const float*)d_in[32];
    const float* dout_W  = (const float*)d_in[33];
    const float* dout_b  = (const float*)d_in[34];
    // d_in[35] = mask: statically [0]*512+[1]*512 per batch -> vis = arange(512)

    float* ws  = (float*)d_ws;
    float* out = (float*)d_out;

    // ---- workspace: 5 aliased slots, total 33,554,432 floats = 128 MiB ----
    // A0 [0, 8.39M):        XV[1-2], XS[4-5], SA[12-13], LNDXV[18-20]
    // A1 [8.39M, 16.78M):   Z[4-8]=YS[8-9] (in-place), QA|KA[11-12], Kv|Vv[20-21]
    // A2 [16.78M, 25.17M):  XC[5-8], VA|OA[11-14], DXV[16-18]
    // A3 [25.17M, 29.36M):  T[2-9], LNY[10-11], Y2[14-15]
    // A4 [29.36M, 33.55M):  HR[3-4], G/dtBC/DT/CUMA[6-8], Y1[9-14],
    //                       G1/HCQ[15-16], masked-chain scratch[17+]
    float* A0 = ws;
    float* A1 = ws + 8388608;
    float* A2 = ws + 16777216;
    float* A3 = ws + 25165824;
    float* A4 = ws + 29360128;

    float* XV    = A0;
    float* XS    = A0;
    float* SA    = A0;
    float* LNDXV = A0;
    float* Z     = A1;          // YS aliases Z (in-place gating)
    float* QA    = A1;
    float* KA    = A1 + 4194304;
    float* Kv    = A1;
    float* Vv    = A1 + 4194304;
    float* XC    = A2;
    float* VA    = A2;
    float* OA    = A2 + 4194304;
    float* DXV   = A2;
    float* T     = A3;
    float* LNY   = A3;
    float* Y2    = A3;
    float* HR    = A4;
    float* G     = A4;          // 2,097,152
    float* dtBC  = A4 + 2097152;  // 589,824
    float* DT    = A4 + 2686976;  // 65,536
    float* CUMA  = A4 + 2752512;  // 65,536
    float* Y1    = A4;
    float* G1    = A4;            // 262,144
    float* HCQ   = A4 + 262144;   // 262,144
    float* dxm   = A4 + 524288;   // 1,024
    float* lnm   = A4 + 525312;   // 1,024
    float* qm    = A4 + 526336;   // 1,024
    float* km    = A4 + 527360;   // 1,024
    float* vm    = A4 + 528384;   // 1,024
    float* OBm   = A4 + 529408;   // 8,192
    float* ydm   = A4 + 537600;   // 8,192
    float* outm  = A4 + 545792;   // 16,384 -> ends at A4 + 562,176

    const long long LL0 = 0;

    // ---- encoder ----
    layernorm_k<<<4096, 256, 0, stream>>>(x, XV, ln0_w, ln0_b, 2048, 512, (long long)1024 * 2048);
    gemm(stream, false, 4096, 1024, 2048, XV, 2048, LL0, LL0, in_W, 2048, LL0, LL0,
         T, 1024, LL0, LL0, nullptr, nullptr, 0, 1.f, 1, 1);
    rmsnorm_k<<<4096, 256, 0, stream>>>(T, HR, rms_w, 1024);
    gemm(stream, false, 4096, 2048, 1024, HR, 1024, LL0, LL0, exp_W, 1024, LL0, LL0,
         XS, 2048, LL0, LL0, nullptr, nullptr, 0, 1.f, 1, 1);
    gemm(stream, false, 4096, 2048, 1024, HR, 1024, LL0, LL0, exp_W + (long long)2048 * 1024, 1024,
         LL0, LL0, Z, 2048, LL0, LL0, nullptr, nullptr, 0, 1.f, 1, 1);
    conv_k<<<32768, 256, 0, stream>>>(XS, conv_W, XC);
    gemm(stream, false, 4096, 144, 2048, XC, 2048, LL0, LL0, xproj_W, 2048, LL0, LL0,
         dtBC, 144, LL0, LL0, nullptr, nullptr, 0, 1.f, 1, 1);
    dt_k<<<256, 256, 0, stream>>>(dtBC, dt_bias, DT);
    cuma_k<<<dim3(16, 8), 64, 0, stream>>>(DT, A_log, CUMA);
    gemm(stream, false, 512, 512, 64, dtBC + 80, 144, (long long)512 * 144, LL0,
         dtBC + 16, 144, (long long)512 * 144, LL0,
         G, 512, (long long)512 * 512, LL0, nullptr, nullptr, 0, 1.f, 1, 8);
    ssd_apply_k<<<dim3(32, 16, 8), 256, 0, stream>>>(G, CUMA, DT, XC, Z, Dv, Z /*YS in-place*/);
    gemm(stream, false, 4096, 1024, 2048, Z /*YS*/, 2048, LL0, LL0, outp_W, 2048, LL0, LL0,
         Y1, 1024, LL0, LL0, outp_b, T, 1024, 1.f, 1, 1);
    // ---- encoder attention ----
    layernorm_k<<<4096, 256, 0, stream>>>(Y1, LNY, n1_w, n1_b, 1024, 4096, LL0);
    gemm(stream, false, 4096, 1024, 1024, LNY, 1024, LL0, LL0, aWq, 1024, LL0, LL0,
         QA, 1024, LL0, LL0, nullptr, nullptr, 0, 1.f, 1, 1);
    gemm(stream, false, 4096, 1024, 1024, LNY, 1024, LL0, LL0, aWk, 1024, LL0, LL0,
         KA, 1024, LL0, LL0, nullptr, nullptr, 0, 1.f, 1, 1);
    gemm(stream, false, 4096, 1024, 1024, LNY, 1024, LL0, LL0, aWv, 1024, LL0, LL0,
         VA, 1024, LL0, LL0, nullptr, nullptr, 0, 1.f, 1, 1);
    gemm(stream, false, 512, 512, 256, QA, 1024, (long long)512 * 1024, 256,
         KA, 1024, (long long)512 * 1024, 256,
         SA, 512, (long long)4 * 512 * 512, (long long)512 * 512,
         nullptr, nullptr, 0, 1.f / 16.f, 4, 32);
    softmax_k<<<16384, 256, 0, stream>>>(SA);
    gemm(stream, true, 512, 256, 512, SA, 512, (long long)4 * 512 * 512, (long long)512 * 512,
         VA, 1024, (long long)512 * 1024, 256,
         OA, 1024, (long long)512 * 1024, 256, nullptr, nullptr, 0, 1.f, 4, 32);
    gemm(stream, false, 4096, 1024, 1024, OA, 1024, LL0, LL0, aWo, 1024, LL0, LL0,
         Y2, 1024, LL0, LL0, aWo_b, Y1, 1024, 1.f, 1, 1);
    // ---- quantize ----
    gemm(stream, false, 4096, 64, 1024, Y2, 1024, LL0, LL0, h_W, 1024, LL0, LL0,
         G1, 64, LL0, LL0, h_b, nullptr, 0, 1.f, 1, 1);
    hc_quant_k<<<4096, 64, 0, stream>>>(G1, h_lnw, h_lnb, HCQ);
    // ---- decoder (collapsed masked rows) ----
    gemm(stream, false, 4096, 1024, 64, HCQ, 64, LL0, LL0, e2d_W, 64, LL0, LL0,
         DXV, 1024, LL0, LL0, nullptr, nullptr, 0, 1.f, 1, 1);
    dxm_k<<<4, 256, 0, stream>>>(mtok, e2d_W, dxm);
    layernorm_k<<<1, 256, 0, stream>>>(dxm, lnm, dn_w, dn_b, 1024, 1, LL0);
    layernorm_k<<<4096, 256, 0, stream>>>(DXV, LNDXV, dn_w, dn_b, 1024, 4096, LL0);
    projm_k<<<12, 256, 0, stream>>>(lnm, bWq, bWk, bWv, qm, km, vm);
    gemm(stream, false, 4096, 1024, 1024, LNDXV, 1024, LL0, LL0, bWk, 1024, LL0, LL0,
         Kv, 1024, LL0, LL0, nullptr, nullptr, 0, 1.f, 1, 1);
    gemm(stream, false, 4096, 1024, 1024, LNDXV, 1024, LL0, LL0, bWv, 1024, LL0, LL0,
         Vv, 1024, LL0, LL0, nullptr, nullptr, 0, 1.f, 1, 1);
    dec_attn_k<<<dim3(4, 8), 256, 0, stream>>>(Kv, Vv, qm, km, vm, OBm);
    ydm_k<<<32, 256, 0, stream>>>(OBm, bWo, bWo_b, dxm, ydm);
    outm_k<<<64, 256, 0, stream>>>(ydm, dout_W, dout_b, outm);
    bcast_k<<<8192, 256, 0, stream>>>(outm, out);
}

// Round 3
// 2121.466 us; speedup vs baseline: 1.7418x; 1.7418x over previous
//
#include <hip/hip_runtime.h>

// ---------------------------------------------------------------------------
// B=8, N=1024, CIN=2048, HID=1024, HC=64, LV=512, NH_SSD=16, HD=128, DS=64.
// Encoder rows = 4096. Decoder collapsed to 1 row/batch (mask_token rows
// identical). Encoder GEMMs: split-bf16x3 MFMA (f32-grade precision).
// Decoder K/V GEMMs: plain bf16 MFMA. Small/ragged GEMMs stay f32 VALU.
// ---------------------------------------------------------------------------

typedef short bf16x8 __attribute__((ext_vector_type(8)));
typedef float f32x4 __attribute__((ext_vector_type(4)));

__device__ __forceinline__ unsigned short bf16_rne(float f) {
    unsigned u = __float_as_uint(f);
    unsigned r = u + 0x7FFFu + ((u >> 16) & 1u);
    return (unsigned short)(r >> 16);
}
// Write split pair: dst row stride = 2*width; hi at [c], lo at [width+c].
__device__ __forceinline__ void store_pair(unsigned short* dst, long long row,
                                           int width, int c, float v) {
    unsigned short hi = bf16_rne(v);
    float fhi = __uint_as_float(((unsigned)hi) << 16);
    unsigned short lo = bf16_rne(v - fhi);
    long long base = row * (2LL * width);
    dst[base + c] = hi;
    dst[base + width + c] = lo;
}

// ---------------------------------------------------------------------------
// Reduction helpers (blockDim 256)
// ---------------------------------------------------------------------------
__device__ __forceinline__ float block_sum256(float v) {
    #pragma unroll
    for (int o = 32; o > 0; o >>= 1) v += __shfl_xor(v, o, 64);
    __shared__ float sm[4];
    int w = threadIdx.x >> 6;
    __syncthreads();
    if ((threadIdx.x & 63) == 0) sm[w] = v;
    __syncthreads();
    return sm[0] + sm[1] + sm[2] + sm[3];
}
__device__ __forceinline__ float block_max256(float v) {
    #pragma unroll
    for (int o = 32; o > 0; o >>= 1) v = fmaxf(v, __shfl_xor(v, o, 64));
    __shared__ float smx[4];
    int w = threadIdx.x >> 6;
    __syncthreads();
    if ((threadIdx.x & 63) == 0) smx[w] = v;
    __syncthreads();
    return fmaxf(fmaxf(smx[0], smx[1]), fmaxf(smx[2], smx[3]));
}

// ---------------------------------------------------------------------------
// MFMA GEMM (split-bf16): C[m,n] = sum_k A[m,k]*W[n,k] (+bias) (+res)
// A2: M x 2K bf16 (hi | lo halves per row), B2: N x 2K bf16 likewise.
// NPASS=3: hi*hi + lo*hi + hi*lo (f32-grade). NPASS=1: hi*hi only.
// Tile 128x128, BK=32, 4 waves; wave computes 64x64 via 4x4 mfma_16x16x32.
// M, N multiples of 128; K multiple of 32.
// ---------------------------------------------------------------------------
template<int NPASS>
__global__ __launch_bounds__(256, 2) void gemm_bf16_k(
    int M, int N, int K,
    const unsigned short* __restrict__ A2,
    const unsigned short* __restrict__ B2,
    float* __restrict__ C, int ldc,
    const float* __restrict__ bias,
    const float* __restrict__ res, int ldr)
{
    // 4 LDS tiles, 128 rows x 32 bf16, row stride 40 ushorts (80 B, 16B-aligned)
    __shared__ unsigned short Ah[128 * 40];
    __shared__ unsigned short Bh[128 * 40];
    __shared__ unsigned short Al[128 * 40];
    __shared__ unsigned short Bl[128 * 40];

    const int t    = threadIdx.x;
    const int m0   = blockIdx.y * 128;
    const int n0   = blockIdx.x * 128;
    const int lane = t & 63, wave = t >> 6;
    const int wm   = (wave >> 1) * 64, wn = (wave & 1) * 64;
    const int lr   = lane & 15, quad = lane >> 4;

    f32x4 acc[4][4];
    #pragma unroll
    for (int i = 0; i < 4; ++i)
        #pragma unroll
        for (int j = 0; j < 4; ++j) acc[i][j] = (f32x4){0.f, 0.f, 0.f, 0.f};

    const int srow = t >> 2;            // 0..63
    const int scol = (t & 3) * 8;       // ushort offset within 32-wide row
    const long long ld2 = 2LL * K;

    for (int k0 = 0; k0 < K; k0 += 32) {
        __syncthreads();
        // stage A/B tiles (rows srow and srow+64 of the 128-row tile)
        #pragma unroll
        for (int half = 0; half < 2; ++half) {
            int r = srow + half * 64;
            const unsigned short* pAh = A2 + (long long)(m0 + r) * ld2 + k0 + scol;
            const unsigned short* pBh = B2 + (long long)(n0 + r) * ld2 + k0 + scol;
            *(uint4*)&Ah[r * 40 + scol] = *(const uint4*)pAh;
            *(uint4*)&Bh[r * 40 + scol] = *(const uint4*)pBh;
            if (NPASS == 3) {
                *(uint4*)&Al[r * 40 + scol] = *(const uint4*)(pAh + K);
                *(uint4*)&Bl[r * 40 + scol] = *(const uint4*)(pBh + K);
            }
        }
        __syncthreads();

        bf16x8 ah[4], bh[4], al[4], bl[4];
        #pragma unroll
        for (int i = 0; i < 4; ++i) {
            int ra = (wm + i * 16 + lr) * 40 + quad * 8;
            int rb = (wn + i * 16 + lr) * 40 + quad * 8;
            ah[i] = *(const bf16x8*)&Ah[ra];
            bh[i] = *(const bf16x8*)&Bh[rb];
            if (NPASS == 3) {
                al[i] = *(const bf16x8*)&Al[ra];
                bl[i] = *(const bf16x8*)&Bl[rb];
            }
        }
        #pragma unroll
        for (int mi = 0; mi < 4; ++mi)
            #pragma unroll
            for (int ni = 0; ni < 4; ++ni) {
                acc[mi][ni] = __builtin_amdgcn_mfma_f32_16x16x32_bf16(
                    ah[mi], bh[ni], acc[mi][ni], 0, 0, 0);
                if (NPASS == 3) {
                    acc[mi][ni] = __builtin_amdgcn_mfma_f32_16x16x32_bf16(
                        al[mi], bh[ni], acc[mi][ni], 0, 0, 0);
                    acc[mi][ni] = __builtin_amdgcn_mfma_f32_16x16x32_bf16(
                        ah[mi], bl[ni], acc[mi][ni], 0, 0, 0);
                }
            }
    }

    // Epilogue: D lane layout col=lane&15, row=quad*4+r
    #pragma unroll
    for (int mi = 0; mi < 4; ++mi)
        #pragma unroll
        for (int ni = 0; ni < 4; ++ni) {
            int col = n0 + wn + ni * 16 + lr;
            float bv = bias ? bias[col] : 0.f;
            #pragma unroll
            for (int r = 0; r < 4; ++r) {
                int row = m0 + wm + mi * 16 + quad * 4 + r;
                float v = acc[mi][ni][r] + bv;
                if (res) v += res[(long long)row * ldr + col];
                C[(long long)row * ldc + col] = v;
            }
        }
}

// ---------------------------------------------------------------------------
// Tiled f32 GEMM (kept for small/ragged/batched cases)
// ---------------------------------------------------------------------------
template<bool BIsKN>
__global__ __launch_bounds__(256) void gemm_k(
    int M, int N, int K,
    const float* __restrict__ A, int lda, long long sAb, long long sAh,
    const float* __restrict__ B, int ldb, long long sBb, long long sBh,
    float* __restrict__ C, int ldc, long long sCb, long long sCh,
    const float* __restrict__ bias,
    const float* __restrict__ res, int ldr,
    float alpha, int nh)
{
    __shared__ float As[32][132];
    __shared__ float Bs[32][132];
    const int z  = blockIdx.z;
    const int bb = z / nh, hh = z - bb * nh;
    A += bb * sAb + hh * sAh;
    B += bb * sBb + hh * sBh;
    C += bb * sCb + hh * sCh;
    const int n0 = blockIdx.x * 128;
    const int m0 = blockIdx.y * 128;
    const int t  = threadIdx.x;
    const int tx = t & 15, ty = t >> 4;

    float acc[4][16];
    #pragma unroll
    for (int a = 0; a < 4; ++a)
        #pragma unroll
        for (int q = 0; q < 16; ++q) acc[a][q] = 0.f;

    const int ka  = (t & 7) << 2;
    const int ra  = t >> 3;
    const int nb2 = (t & 31) << 2;
    const int kb2 = t >> 5;

    for (int k0 = 0; k0 < K; k0 += 32) {
        __syncthreads();
        #pragma unroll
        for (int i = 0; i < 4; ++i) {
            int row = m0 + ra + i * 32;
            float4 v = *(const float4*)(A + (long long)row * lda + (k0 + ka));
            As[ka + 0][ra + i * 32] = v.x;
            As[ka + 1][ra + i * 32] = v.y;
            As[ka + 2][ra + i * 32] = v.z;
            As[ka + 3][ra + i * 32] = v.w;
        }
        if (!BIsKN) {
            #pragma unroll
            for (int i = 0; i < 4; ++i) {
                int row = n0 + ra + i * 32;
                float4 v = make_float4(0.f, 0.f, 0.f, 0.f);
                if (row < N) v = *(const float4*)(B + (long long)row * ldb + (k0 + ka));
                Bs[ka + 0][ra + i * 32] = v.x;
                Bs[ka + 1][ra + i * 32] = v.y;
                Bs[ka + 2][ra + i * 32] = v.z;
                Bs[ka + 3][ra + i * 32] = v.w;
            }
        } else {
            #pragma unroll
            for (int i = 0; i < 4; ++i) {
                int kr  = kb2 + i * 8;
                int col = n0 + nb2;
                float4 v = make_float4(0.f, 0.f, 0.f, 0.f);
                if (col < N) v = *(const float4*)(B + (long long)(k0 + kr) * ldb + col);
                *(float4*)&Bs[kr][nb2] = v;
            }
        }
        __syncthreads();
        #pragma unroll
        for (int kk = 0; kk < 32; ++kk) {
            float a[8], bm[8];
            *(float4*)&a[0]  = *(const float4*)&As[kk][ty * 4];
            *(float4*)&a[4]  = *(const float4*)&As[kk][64 + ty * 4];
            *(float4*)&bm[0] = *(const float4*)&Bs[kk][tx * 4];
            *(float4*)&bm[4] = *(const float4*)&Bs[kk][64 + tx * 4];
            #pragma unroll
            for (int ri = 0; ri < 2; ++ri)
                #pragma unroll
                for (int ci = 0; ci < 2; ++ci)
                    #pragma unroll
                    for (int i = 0; i < 4; ++i)
                        #pragma unroll
                        for (int j = 0; j < 4; ++j)
                            acc[ri * 2 + ci][i * 4 + j] =
                                fmaf(a[ri * 4 + i], bm[ci * 4 + j], acc[ri * 2 + ci][i * 4 + j]);
        }
    }

    #pragma unroll
    for (int ri = 0; ri < 2; ++ri)
        #pragma unroll
        for (int ci = 0; ci < 2; ++ci) {
            int colb = n0 + ci * 64 + tx * 4;
            if (colb >= N) continue;
            float4 bv = make_float4(0.f, 0.f, 0.f, 0.f);
            if (bias) bv = *(const float4*)(bias + colb);
            #pragma unroll
            for (int i = 0; i < 4; ++i) {
                int row = m0 + ri * 64 + ty * 4 + i;
                float4 o;
                o.x = alpha * acc[ri * 2 + ci][i * 4 + 0] + bv.x;
                o.y = alpha * acc[ri * 2 + ci][i * 4 + 1] + bv.y;
                o.z = alpha * acc[ri * 2 + ci][i * 4 + 2] + bv.z;
                o.w = alpha * acc[ri * 2 + ci][i * 4 + 3] + bv.w;
                if (res) {
                    float4 rv = *(const float4*)(res + (long long)row * ldr + colb);
                    o.x += rv.x; o.y += rv.y; o.z += rv.z; o.w += rv.w;
                }
                *(float4*)(C + (long long)row * ldc + colb) = o;
            }
        }
}

// ---------------------------------------------------------------------------
// Elementwise / norm kernels
// ---------------------------------------------------------------------------
// f32 -> split bf16 pair. n elems, K = row width (pow2, log2 passed).
__global__ __launch_bounds__(256) void pairify_k(
    const float* __restrict__ src, unsigned short* __restrict__ dst,
    int k_log2, long long n)
{
    long long idx = (long long)blockIdx.x * 256 + threadIdx.x;
    if (idx >= n) return;
    long long r = idx >> k_log2;
    int c = (int)(idx & ((1 << k_log2) - 1));
    store_pair(dst, r, 1 << k_log2, c, src[idx]);
}

// LayerNorm -> f32 out
__global__ __launch_bounds__(256) void layernorm_k(
    const float* __restrict__ in, float* __restrict__ out,
    const float* __restrict__ w, const float* __restrict__ b,
    int width, int rows_per_b, long long in_bstride)
{
    long long r = blockIdx.x;
    const float* x = in + (r / rows_per_b) * in_bstride + (r % rows_per_b) * (long long)width;
    int t = threadIdx.x;
    float s = 0.f;
    for (int c = t; c < width; c += 256) s += x[c];
    s = block_sum256(s);
    float m = s / (float)width;
    float vs = 0.f;
    for (int c = t; c < width; c += 256) { float d = x[c] - m; vs += d * d; }
    vs = block_sum256(vs);
    float rs = 1.f / sqrtf(vs / (float)width + 1e-5f);
    float* o = out + r * (long long)width;
    for (int c = t; c < width; c += 256) o[c] = (x[c] - m) * rs * w[c] + b[c];
}

// LayerNorm -> split bf16 pair out
__global__ __launch_bounds__(256) void layernorm_pair_k(
    const float* __restrict__ in, unsigned short* __restrict__ out2,
    const float* __restrict__ w, const float* __restrict__ b,
    int width, int rows_per_b, long long in_bstride)
{
    long long r = blockIdx.x;
    const float* x = in + (r / rows_per_b) * in_bstride + (r % rows_per_b) * (long long)width;
    int t = threadIdx.x;
    float s = 0.f;
    for (int c = t; c < width; c += 256) s += x[c];
    s = block_sum256(s);
    float m = s / (float)width;
    float vs = 0.f;
    for (int c = t; c < width; c += 256) { float d = x[c] - m; vs += d * d; }
    vs = block_sum256(vs);
    float rs = 1.f / sqrtf(vs / (float)width + 1e-5f);
    for (int c = t; c < width; c += 256)
        store_pair(out2, r, width, c, (x[c] - m) * rs * w[c] + b[c]);
}

// RMSNorm -> split bf16 pair out
__global__ __launch_bounds__(256) void rmsnorm_pair_k(
    const float* __restrict__ in, unsigned short* __restrict__ out2,
    const float* __restrict__ w, int width)
{
    long long r = blockIdx.x;
    const float* x = in + r * (long long)width;
    int t = threadIdx.x;
    float s = 0.f;
    for (int c = t; c < width; c += 256) { float v = x[c]; s += v * v; }
    s = block_sum256(s);
    float rs = 1.f / sqrtf(s / (float)width + 1e-5f);
    for (int c = t; c < width; c += 256)
        store_pair(out2, r, width, c, x[c] * rs * w[c]);
}

// In-place row softmax, width 512.
__global__ __launch_bounds__(256) void softmax_k(float* __restrict__ S)
{
    long long r = blockIdx.x;
    float* x = S + r * 512;
    int t = threadIdx.x;
    float v0 = x[t], v1 = x[t + 256];
    float mx = block_max256(fmaxf(v0, v1));
    v0 = expf(v0 - mx); v1 = expf(v1 - mx);
    float sum = block_sum256(v0 + v1);
    float inv = 1.f / sum;
    x[t] = v0 * inv; x[t + 256] = v1 * inv;
}

// Depthwise-grouped causal conv
__global__ __launch_bounds__(256) void conv_k(
    const float* __restrict__ XS, const float* __restrict__ W, float* __restrict__ XC)
{
    int idx = blockIdx.x * 256 + threadIdx.x;
    int o = idx & 2047;
    int tt = (idx >> 11) & 511;
    int b = idx >> 20;
    int g2 = (o >> 1) << 1;
    const float* Wo = W + o * 8;
    float acc = 0.f;
    #pragma unroll
    for (int k = 0; k < 4; ++k) {
        int ts = tt + k - 3;
        if (ts >= 0) {
            const float* xr = XS + ((long long)(b * 512 + ts)) * 2048;
            acc = fmaf(Wo[k], xr[g2], acc);
            acc = fmaf(Wo[4 + k], xr[g2 + 1], acc);
        }
    }
    XC[idx] = acc;
}

__global__ __launch_bounds__(256) void dt_k(
    const float* __restrict__ dtBC, const float* __restrict__ dt_bias, float* __restrict__ DT)
{
    int idx = blockIdx.x * 256 + threadIdx.x;
    int r = idx >> 4, h = idx & 15;
    float xv = dtBC[r * 144 + h] + dt_bias[h];
    DT[idx] = (xv > 20.f) ? xv : log1pf(expf(xv));
}

__global__ __launch_bounds__(64) void cuma_k(
    const float* __restrict__ DT, const float* __restrict__ A_log, float* __restrict__ CUMA)
{
    int h = blockIdx.x, b = blockIdx.y;
    int ln = threadIdx.x;
    float Ah = -expf(A_log[h]);
    float v[8];
    float run = 0.f;
    #pragma unroll
    for (int i = 0; i < 8; ++i) {
        run += Ah * DT[((b * 512) + (ln * 8 + i)) * 16 + h];
        v[i] = run;
    }
    float tot = run;
    float sc = tot;
    #pragma unroll
    for (int o = 1; o <= 32; o <<= 1) {
        float u = __shfl_up(sc, o, 64);
        if (ln >= o) sc += u;
    }
    float excl = sc - tot;
    #pragma unroll
    for (int i = 0; i < 8; ++i)
        CUMA[(b * 16 + h) * 512 + ln * 8 + i] = excl + v[i];
}

// SSD apply + D-skip + silu(z) gate -> split bf16 pair (row width 2048)
__global__ __launch_bounds__(256) void ssd_apply_k(
    const float* __restrict__ G, const float* __restrict__ CUMA,
    const float* __restrict__ DT, const float* __restrict__ XC,
    const float* __restrict__ Z, const float* __restrict__ Dv,
    unsigned short* __restrict__ YS2)
{
    int lt = blockIdx.x, h = blockIdx.y, b = blockIdx.z;
    int t = threadIdx.x;
    int p = t & 127, lg = t >> 7;
    int li = t >> 4, si = t & 15;
    __shared__ float XCs[16][128];
    __shared__ float Ws[16][16];
    float acc[8];
    #pragma unroll
    for (int r = 0; r < 8; ++r) acc[r] = 0.f;

    int lglob = lt * 16 + li;
    float cAl = CUMA[(b * 16 + h) * 512 + lglob];

    for (int st = 0; st <= lt; ++st) {
        __syncthreads();
        #pragma unroll
        for (int j = 0; j < 8; ++j) {
            int idx = t + j * 256;
            int sr = idx >> 7, sc = idx & 127;
            XCs[sr][sc] = XC[((long long)(b * 512 + st * 16 + sr)) * 2048 + h * 128 + sc];
        }
        int sglob = st * 16 + si;
        float wv = 0.f;
        if (sglob <= lglob) {
            float cAs = CUMA[(b * 16 + h) * 512 + sglob];
            wv = G[((long long)(b * 512 + lglob)) * 512 + sglob] * expf(cAl - cAs)
                 * DT[(b * 512 + sglob) * 16 + h];
        }
        Ws[li][si] = wv;
        __syncthreads();
        #pragma unroll
        for (int ss = 0; ss < 16; ++ss) {
            float xv = XCs[ss][p];
            #pragma unroll
            for (int r = 0; r < 8; ++r)
                acc[r] = fmaf(Ws[lg + r * 2][ss], xv, acc[r]);
        }
    }
    float Dh = Dv[h];
    #pragma unroll
    for (int r = 0; r < 8; ++r) {
        int l = lt * 16 + lg + r * 2;
        long long row = (long long)(b * 512 + l);
        long long base = row * 2048 + h * 128 + p;
        float zz = Z[base];
        float sil = zz / (1.f + expf(-zz));
        store_pair(YS2, row, 2048, h * 128 + p, (acc[r] + XC[base] * Dh) * sil);
    }
}

// hc = LayerNorm64(G1) -> {-1,+1}
__global__ __launch_bounds__(64) void hc_quant_k(
    const float* __restrict__ G1, const float* __restrict__ w,
    const float* __restrict__ b, float* __restrict__ HCQ)
{
    int r = blockIdx.x, ln = threadIdx.x;
    float v = G1[r * 64 + ln];
    float s = v;
    #pragma unroll
    for (int o = 32; o > 0; o >>= 1) s += __shfl_xor(s, o, 64);
    float m = s * (1.f / 64.f);
    float d = v - m;
    float vs = d * d;
    #pragma unroll
    for (int o = 32; o > 0; o >>= 1) vs += __shfl_xor(vs, o, 64);
    vs *= (1.f / 64.f);
    float hc = d * (1.f / sqrtf(vs + 1e-5f)) * w[ln] + b[ln];
    HCQ[r * 64 + ln] = (hc > 0.f) ? 1.f : -1.f;
}

__global__ __launch_bounds__(256) void dxm_k(
    const float* __restrict__ mtok, const float* __restrict__ e2d, float* __restrict__ dxm)
{
    int c = blockIdx.x * 256 + threadIdx.x;
    float acc = 0.f;
    #pragma unroll
    for (int j = 0; j < 64; ++j) acc = fmaf(mtok[j], e2d[c * 64 + j], acc);
    dxm[c] = acc;
}

__global__ __launch_bounds__(256) void projm_k(
    const float* __restrict__ lnm,
    const float* __restrict__ bWq, const float* __restrict__ bWk, const float* __restrict__ bWv,
    float* __restrict__ qm, float* __restrict__ km, float* __restrict__ vm)
{
    int idx = blockIdx.x * 256 + threadIdx.x;
    int sel = idx >> 10, c = idx & 1023;
    const float* W = (sel == 0) ? bWq : (sel == 1) ? bWk : bWv;
    float* O = (sel == 0) ? qm : (sel == 1) ? km : vm;
    const float* wr = W + (long long)c * 1024;
    float acc = 0.f;
    for (int j = 0; j < 1024; j += 4) {
        float4 a = *(const float4*)(lnm + j);
        float4 w4 = *(const float4*)(wr + j);
        acc = fmaf(a.x, w4.x, fmaf(a.y, w4.y, fmaf(a.z, w4.z, fmaf(a.w, w4.w, acc))));
    }
    O[c] = acc;
}

// Collapsed decoder attention: 1 query/(b,h); keys = 512 visible + mask key x512.
__global__ __launch_bounds__(256) void dec_attn_k(
    const float* __restrict__ Kv, const float* __restrict__ Vv,
    const float* __restrict__ qm, const float* __restrict__ km,
    const float* __restrict__ vm, float* __restrict__ OBm)
{
    int h = blockIdx.x, b = blockIdx.y;
    int t = threadIdx.x;
    __shared__ __align__(16) float qs[256];
    __shared__ __align__(16) float ps[512];
    qs[t] = qm[h * 256 + t];
    __syncthreads();
    float s[2];
    #pragma unroll
    for (int i = 0; i < 2; ++i) {
        int r = t + i * 256;
        const float* kr = Kv + ((long long)(b * 512 + r)) * 1024 + h * 256;
        float acc = 0.f;
        for (int c = 0; c < 256; c += 4) {
            float4 k4 = *(const float4*)(kr + c);
            float4 q4 = *(const float4*)(qs + c);
            acc = fmaf(k4.x, q4.x, fmaf(k4.y, q4.y, fmaf(k4.z, q4.z, fmaf(k4.w, q4.w, acc))));
        }
        s[i] = acc * (1.f / 16.f);
    }
    float accm = 0.f;
    for (int c = 0; c < 256; c += 4) {
        float4 k4 = *(const float4*)(km + h * 256 + c);
        float4 q4 = *(const float4*)(qs + c);
        accm = fmaf(k4.x, q4.x, fmaf(k4.y, q4.y, fmaf(k4.z, q4.z, fmaf(k4.w, q4.w, accm))));
    }
    float smv = accm * (1.f / 16.f);
    float mx = block_max256(fmaxf(fmaxf(s[0], s[1]), smv));
    float p0 = expf(s[0] - mx), p1 = expf(s[1] - mx);
    ps[t] = p0; ps[t + 256] = p1;
    float pm = expf(smv - mx) * 512.f;
    float sum = block_sum256(p0 + p1) + pm;
    float inv = 1.f / sum;
    __syncthreads();
    float o = pm * vm[h * 256 + t];
    const float* vcol = Vv + (long long)b * 512 * 1024 + h * 256 + t;
    for (int j = 0; j < 512; ++j)
        o = fmaf(ps[j], vcol[(long long)j * 1024], o);
    OBm[b * 1024 + h * 256 + t] = o * inv;
}

__global__ __launch_bounds__(256) void ydm_k(
    const float* __restrict__ OBm, const float* __restrict__ bWo,
    const float* __restrict__ bWo_b, const float* __restrict__ dxm,
    float* __restrict__ ydm)
{
    int idx = blockIdx.x * 256 + threadIdx.x;
    int b = idx >> 10, c = idx & 1023;
    const float* ar = OBm + b * 1024;
    const float* wr = bWo + (long long)c * 1024;
    float acc = 0.f;
    for (int j = 0; j < 1024; j += 4) {
        float4 a = *(const float4*)(ar + j);
        float4 w4 = *(const float4*)(wr + j);
        acc = fmaf(a.x, w4.x, fmaf(a.y, w4.y, fmaf(a.z, w4.z, fmaf(a.w, w4.w, acc))));
    }
    ydm[idx] = acc + bWo_b[c] + dxm[c];
}

__global__ __launch_bounds__(256) void outm_k(
    const float* __restrict__ ydm, const float* __restrict__ dout_W,
    const float* __restrict__ dout_b, float* __restrict__ outm)
{
    int idx = blockIdx.x * 256 + threadIdx.x;
    int b = idx >> 11, c = idx & 2047;
    const float* ar = ydm + b * 1024;
    const float* wr = dout_W + (long long)c * 1024;
    float acc = 0.f;
    for (int j = 0; j < 1024; j += 4) {
        float4 a = *(const float4*)(ar + j);
        float4 w4 = *(const float4*)(wr + j);
        acc = fmaf(a.x, w4.x, fmaf(a.y, w4.y, fmaf(a.z, w4.z, fmaf(a.w, w4.w, acc))));
    }
    outm[idx] = acc + dout_b[c];
}

__global__ __launch_bounds__(256) void bcast_k(
    const float* __restrict__ outm, float* __restrict__ out)
{
    int idx = blockIdx.x * 256 + threadIdx.x;
    int c4 = idx & 511;
    int b = idx >> 18;
    ((float4*)out)[idx] = ((const float4*)outm)[b * 512 + c4];
}

// ---------------------------------------------------------------------------
// Host-side launcher
// ---------------------------------------------------------------------------
static inline void gemm(hipStream_t s, bool bkn, int M, int N, int K,
                        const float* A, int lda, long long sAb, long long sAh,
                        const float* B, int ldb, long long sBb, long long sBh,
                        float* C, int ldc, long long sCb, long long sCh,
                        const float* bias, const float* res, int ldr,
                        float alpha, int nh, int batches)
{
    dim3 g((N + 127) / 128, (M + 127) / 128, batches);
    if (bkn)
        gemm_k<true><<<g, 256, 0, s>>>(M, N, K, A, lda, sAb, sAh, B, ldb, sBb, sBh,
                                       C, ldc, sCb, sCh, bias, res, ldr, alpha, nh);
    else
        gemm_k<false><<<g, 256, 0, s>>>(M, N, K, A, lda, sAb, sAh, B, ldb, sBb, sBh,
                                        C, ldc, sCb, sCh, bias, res, ldr, alpha, nh);
}

static inline void gemm3(hipStream_t s, int M, int N, int K,
                         const unsigned short* A2, const unsigned short* B2,
                         float* C, int ldc, const float* bias,
                         const float* res, int ldr)
{
    dim3 g(N / 128, M / 128);
    gemm_bf16_k<3><<<g, 256, 0, s>>>(M, N, K, A2, B2, C, ldc, bias, res, ldr);
}
static inline void gemm1(hipStream_t s, int M, int N, int K,
                         const unsigned short* A2, const unsigned short* B2,
                         float* C, int ldc)
{
    dim3 g(N / 128, M / 128);
    gemm_bf16_k<1><<<g, 256, 0, s>>>(M, N, K, A2, B2, C, ldc, nullptr, nullptr, 0);
}
static inline void pairify(hipStream_t s, const float* src, unsigned short* dst,
                           int k_log2, long long n)
{
    pairify_k<<<(int)((n + 255) / 256), 256, 0, s>>>(src, dst, k_log2, n);
}

extern "C" void kernel_launch(void* const* d_in, const int* in_sizes, int n_in,
                              void* d_out, int out_size, void* d_ws, size_t ws_size,
                              hipStream_t stream)
{
    const float* x       = (const float*)d_in[0];
    const float* ln0_w   = (const float*)d_in[1];
    const float* ln0_b   = (const float*)d_in[2];
    const float* in_W    = (const float*)d_in[3];
    const float* rms_w   = (const float*)d_in[4];
    const float* exp_W   = (const float*)d_in[5];
    const float* conv_W  = (const float*)d_in[6];
    const float* xproj_W = (const float*)d_in[7];
    const float* dt_bias = (const float*)d_in[8];
    const float* A_log   = (const float*)d_in[9];
    const float* Dv      = (const float*)d_in[10];
    const float* outp_W  = (const float*)d_in[11];
    const float* outp_b  = (const float*)d_in[12];
    const float* n1_w    = (const float*)d_in[13];
    const float* n1_b    = (const float*)d_in[14];
    const float* aWq     = (const float*)d_in[15];
    const float* aWk     = (const float*)d_in[16];
    const float* aWv     = (const float*)d_in[17];
    const float* aWo     = (const float*)d_in[18];
    const float* aWo_b   = (const float*)d_in[19];
    const float* h_W     = (const float*)d_in[20];
    const float* h_b     = (const float*)d_in[21];
    const float* h_lnw   = (const float*)d_in[22];
    const float* h_lnb   = (const float*)d_in[23];
    const float* mtok    = (const float*)d_in[24];
    const float* e2d_W   = (const float*)d_in[25];
    const float* dn_w    = (const float*)d_in[26];
    const float* dn_b    = (const float*)d_in[27];
    const float* bWq     = (const float*)d_in[28];
    const float* bWk     = (const float*)d_in[29];
    const float* bWv     = (const float*)d_in[30];
    const float* bWo     = (const float*)d_in[31];
    const float* bWo_b   = (const float*)d_in[32];
    const float* dout_W  = (const float*)d_in[33];
    const float* dout_b  = (const float*)d_in[34];

    float* ws  = (float*)d_ws;
    float* out = (float*)d_out;

    // ---- workspace (float offsets) ----
    // R0 8.39M : XV2/YS2 (bf16 pair, 16.8M ushort)
    // R1 8.39M : XS f32 | SA f32 | DXV f32 (4.19M)
    // R2 8.39M : Z f32 | (VA 4.19M + KA 4.19M) | (bWk2 + bWv2 pairs)
    // R3 8.39M : XC f32 | (QA 4.19M + OA 4.19M) | (Kv 4.19M + Vv 4.19M)
    // R4 4.19M : HR2 / LNY2 / OA2 / LNDXV2 (bf16 pair, 8.39M ushort)
    // R5 4.19M : T
    // R6 4.19M : Y1
    // R7 4.19M : Y2
    // R9 2.88M : G(2.10M)+dtBC(0.59M)+DT+CUMA ; G1/HCQ/smalls alias over G
    // W2 12.58M: encoder weight bf16-pair pool (25.17M ushort)
    float* R0 = ws;
    float* R1 = ws + 8388608;
    float* R2 = ws + 16777216;
    float* R3 = ws + 25165824;
    float* R4 = ws + 33554432;
    float* R5 = ws + 37748736;
    float* R6 = ws + 41943040;
    float* R7 = ws + 46137344;
    float* R9 = ws + 50331648;
    unsigned short* W2 = (unsigned short*)(ws + 53215232);  // 25,165,824 ushorts

    unsigned short* XV2    = (unsigned short*)R0;
    unsigned short* YS2    = (unsigned short*)R0;
    float* XS   = R1;
    float* SA   = R1;
    float* DXV  = R1;
    float* Z    = R2;
    float* VA   = R2;
    float* KA   = R2 + 4194304;
    unsigned short* bWk2 = (unsigned short*)R2;             // 2.10M ushorts
    unsigned short* bWv2 = (unsigned short*)(R2 + 1048576);
    float* XC   = R3;
    float* QA   = R3;
    float* OA   = R3 + 4194304;
    float* Kv   = R3;
    float* Vv   = R3 + 4194304;
    unsigned short* HR2    = (unsigned short*)R4;
    unsigned short* LNY2   = (unsigned short*)R4;
    unsigned short* OA2    = (unsigned short*)R4;
    unsigned short* LNDXV2 = (unsigned short*)R4;
    float* T    = R5;
    float* Y1   = R6;
    float* Y2   = R7;
    float* G    = R9;                 // 2,097,152
    float* dtBC = R9 + 2097152;       // 589,824
    float* DT   = R9 + 2686976;       // 65,536
    float* CUMA = R9 + 2752512;       // 65,536
    float* G1   = R9;                 // alias over dead G
    float* HCQ  = R9 + 262144;
    float* dxm  = R9 + 524288;
    float* lnm  = R9 + 525312;
    float* qm   = R9 + 526336;
    float* km   = R9 + 527360;
    float* vm   = R9 + 528384;
    float* OBm  = R9 + 529408;
    float* ydm  = R9 + 537600;
    float* outm = R9 + 545792;

    unsigned short* in_W2   = W2;                // 1024 x 4096
    unsigned short* exp_W2  = W2 + 4194304;      // 4096 x 2048
    unsigned short* outp_W2 = W2 + 12582912;     // 1024 x 4096
    unsigned short* aWq2    = W2 + 16777216;     // 1024 x 2048
    unsigned short* aWk2    = W2 + 18874368;
    unsigned short* aWv2    = W2 + 20971520;
    unsigned short* aWo2    = W2 + 23068672;

    const long long LL0 = 0;

    // ---- weight conversion (every call; no static caching) ----
    pairify(stream, in_W,   in_W2,   11, 1024LL * 2048);
    pairify(stream, exp_W,  exp_W2,  10, 4096LL * 1024);
    pairify(stream, outp_W, outp_W2, 11, 1024LL * 2048);
    pairify(stream, aWq,    aWq2,    10, 1024LL * 1024);
    pairify(stream, aWk,    aWk2,    10, 1024LL * 1024);
    pairify(stream, aWv,    aWv2,    10, 1024LL * 1024);
    pairify(stream, aWo,    aWo2,    10, 1024LL * 1024);

    // ---- encoder ----
    layernorm_pair_k<<<4096, 256, 0, stream>>>(x, XV2, ln0_w, ln0_b, 2048, 512,
                                               (long long)1024 * 2048);
    gemm3(stream, 4096, 1024, 2048, XV2, in_W2, T, 1024, nullptr, nullptr, 0);
    rmsnorm_pair_k<<<4096, 256, 0, stream>>>(T, HR2, rms_w, 1024);
    gemm3(stream, 4096, 2048, 1024, HR2, exp_W2, XS, 2048, nullptr, nullptr, 0);
    gemm3(stream, 4096, 2048, 1024, HR2, exp_W2 + 2048LL * 2048, Z, 2048,
          nullptr, nullptr, 0);
    conv_k<<<32768, 256, 0, stream>>>(XS, conv_W, XC);
    gemm(stream, false, 4096, 144, 2048, XC, 2048, LL0, LL0, xproj_W, 2048, LL0, LL0,
         dtBC, 144, LL0, LL0, nullptr, nullptr, 0, 1.f, 1, 1);
    dt_k<<<256, 256, 0, stream>>>(dtBC, dt_bias, DT);
    cuma_k<<<dim3(16, 8), 64, 0, stream>>>(DT, A_log, CUMA);
    gemm(stream, false, 512, 512, 64, dtBC + 80, 144, (long long)512 * 144, LL0,
         dtBC + 16, 144, (long long)512 * 144, LL0,
         G, 512, (long long)512 * 512, LL0, nullptr, nullptr, 0, 1.f, 1, 8);
    ssd_apply_k<<<dim3(32, 16, 8), 256, 0, stream>>>(G, CUMA, DT, XC, Z, Dv, YS2);
    gemm3(stream, 4096, 1024, 2048, YS2, outp_W2, Y1, 1024, outp_b, T, 1024);
    // ---- encoder attention ----
    layernorm_pair_k<<<4096, 256, 0, stream>>>(Y1, LNY2, n1_w, n1_b, 1024, 4096, LL0);
    gemm3(stream, 4096, 1024, 1024, LNY2, aWq2, QA, 1024, nullptr, nullptr, 0);
    gemm3(stream, 4096, 1024, 1024, LNY2, aWk2, KA, 1024, nullptr, nullptr, 0);
    gemm3(stream, 4096, 1024, 1024, LNY2, aWv2, VA, 1024, nullptr, nullptr, 0);
    gemm(stream, false, 512, 512, 256, QA, 1024, (long long)512 * 1024, 256,
         KA, 1024, (long long)512 * 1024, 256,
         SA, 512, (long long)4 * 512 * 512, (long long)512 * 512,
         nullptr, nullptr, 0, 1.f / 16.f, 4, 32);
    softmax_k<<<16384, 256, 0, stream>>>(SA);
    gemm(stream, true, 512, 256, 512, SA, 512, (long long)4 * 512 * 512, (long long)512 * 512,
         VA, 1024, (long long)512 * 1024, 256,
         OA, 1024, (long long)512 * 1024, 256, nullptr, nullptr, 0, 1.f, 4, 32);
    pairify(stream, OA, OA2, 10, 4096LL * 1024);
    gemm3(stream, 4096, 1024, 1024, OA2, aWo2, Y2, 1024, aWo_b, Y1, 1024);
    // ---- quantize ----
    gemm(stream, false, 4096, 64, 1024, Y2, 1024, LL0, LL0, h_W, 1024, LL0, LL0,
         G1, 64, LL0, LL0, h_b, nullptr, 0, 1.f, 1, 1);
    hc_quant_k<<<4096, 64, 0, stream>>>(G1, h_lnw, h_lnb, HCQ);
    // ---- decoder (collapsed masked rows) ----
    gemm(stream, false, 4096, 1024, 64, HCQ, 64, LL0, LL0, e2d_W, 64, LL0, LL0,
         DXV, 1024, LL0, LL0, nullptr, nullptr, 0, 1.f, 1, 1);
    dxm_k<<<4, 256, 0, stream>>>(mtok, e2d_W, dxm);
    layernorm_k<<<1, 256, 0, stream>>>(dxm, lnm, dn_w, dn_b, 1024, 1, LL0);
    layernorm_pair_k<<<4096, 256, 0, stream>>>(DXV, LNDXV2, dn_w, dn_b, 1024, 4096, LL0);
    projm_k<<<12, 256, 0, stream>>>(lnm, bWq, bWk, bWv, qm, km, vm);
    pairify(stream, bWk, bWk2, 10, 1024LL * 1024);
    pairify(stream, bWv, bWv2, 10, 1024LL * 1024);
    gemm1(stream, 4096, 1024, 1024, LNDXV2, bWk2, Kv, 1024);
    gemm1(stream, 4096, 1024, 1024, LNDXV2, bWv2, Vv, 1024);
    dec_attn_k<<<dim3(4, 8), 256, 0, stream>>>(Kv, Vv, qm, km, vm, OBm);
    ydm_k<<<32, 256, 0, stream>>>(OBm, bWo, bWo_b, dxm, ydm);
    outm_k<<<64, 256, 0, stream>>>(ydm, dout_W, dout_b, outm);
    bcast_k<<<8192, 256, 0, stream>>>(outm, out);
}

// Round 4
// 1837.866 us; speedup vs baseline: 2.0106x; 1.1543x over previous
//
#include <hip/hip_runtime.h>

// ---------------------------------------------------------------------------
// B=8, N=1024, CIN=2048, HID=1024, HC=64, LV=512, NH_SSD=16, HD=128, DS=64.
// Encoder rows = 4096. Decoder collapsed to 1 row/batch (mask_token rows
// identical). All large GEMMs: split-bf16 MFMA (x3 passes = f32-grade in the
// encoder; x1 post-quantizer). Only the tiny G=C@B^T batched GEMM stays f32.
// ---------------------------------------------------------------------------

typedef short bf16x8 __attribute__((ext_vector_type(8)));
typedef float f32x4 __attribute__((ext_vector_type(4)));

__device__ __forceinline__ unsigned short bf16_rne(float f) {
    unsigned u = __float_as_uint(f);
    unsigned r = u + 0x7FFFu + ((u >> 16) & 1u);
    return (unsigned short)(r >> 16);
}
__device__ __forceinline__ float bf16_tof(unsigned short h) {
    return __uint_as_float(((unsigned)h) << 16);
}
// Split pair: row stride 2*width ushorts; hi at [c], lo at [width+c].
__device__ __forceinline__ void store_pair(unsigned short* dst, long long row,
                                           int width, int c, float v) {
    unsigned short hi = bf16_rne(v);
    unsigned short lo = bf16_rne(v - bf16_tof(hi));
    long long base = row * (2LL * width);
    dst[base + c] = hi;
    dst[base + width + c] = lo;
}

// ---------------------------------------------------------------------------
// Reduction helpers (blockDim 256)
// ---------------------------------------------------------------------------
__device__ __forceinline__ float block_sum256(float v) {
    #pragma unroll
    for (int o = 32; o > 0; o >>= 1) v += __shfl_xor(v, o, 64);
    __shared__ float sm[4];
    int w = threadIdx.x >> 6;
    __syncthreads();
    if ((threadIdx.x & 63) == 0) sm[w] = v;
    __syncthreads();
    return sm[0] + sm[1] + sm[2] + sm[3];
}
__device__ __forceinline__ float block_max256(float v) {
    #pragma unroll
    for (int o = 32; o > 0; o >>= 1) v = fmaxf(v, __shfl_xor(v, o, 64));
    __shared__ float smx[4];
    int w = threadIdx.x >> 6;
    __syncthreads();
    if ((threadIdx.x & 63) == 0) smx[w] = v;
    __syncthreads();
    return fmaxf(fmaxf(smx[0], smx[1]), fmaxf(smx[2], smx[3]));
}

// ---------------------------------------------------------------------------
// Split-bf16 MFMA GEMM: C[m,n] = alpha * sum_k A[m,k]*B[n,k] (+bias) (+res)
// A2/B2: split-pair bf16 (hi at +0, lo at +aLo/bLo from same index).
// NPASS=3: hh + lh + hl (f32-grade). NPASS=1: hh only.
// OUT=0: f32 C (ldc floats). OUT=1: split-pair C (ldc ushorts, lo at +cLo).
// OUT=2: transposed split-pair C[chan][seq] per 512-row batch
//        (b=row>>9 -> C + b*sCb + col*ldc + (row&511), lo at +cLo).
// Batched via blockIdx.z: bb=z/nh, hh=z%nh; strides in element units.
// M mult of 128, K mult of 32; N ragged OK.
// ---------------------------------------------------------------------------
template<int NPASS, int OUT>
__global__ __launch_bounds__(256, 2) void gemm_bf16_k(
    int M, int N, int K,
    const unsigned short* __restrict__ A2, int lda2, int aLo, long long sAb, long long sAh,
    const unsigned short* __restrict__ B2, int ldb2, int bLo, long long sBb, long long sBh,
    void* __restrict__ Cv, int ldc, int cLo, long long sCb, long long sCh,
    const float* __restrict__ bias, const float* __restrict__ res, int ldr,
    float alpha, int nh)
{
    __shared__ unsigned short Ah[128 * 40];
    __shared__ unsigned short Bh[128 * 40];
    __shared__ unsigned short Al[128 * 40];
    __shared__ unsigned short Bl[128 * 40];

    const int z  = blockIdx.z;
    const int bb = z / nh, hh = z - bb * nh;
    A2 += bb * sAb + hh * sAh;
    B2 += bb * sBb + hh * sBh;

    const int t    = threadIdx.x;
    const int m0   = blockIdx.y * 128;
    const int n0   = blockIdx.x * 128;
    const int lane = t & 63, wave = t >> 6;
    const int wm   = (wave >> 1) * 64, wn = (wave & 1) * 64;
    const int lr   = lane & 15, quad = lane >> 4;

    f32x4 acc[4][4];
    #pragma unroll
    for (int i = 0; i < 4; ++i)
        #pragma unroll
        for (int j = 0; j < 4; ++j) acc[i][j] = (f32x4){0.f, 0.f, 0.f, 0.f};

    const int srow = t >> 2;
    const int scol = (t & 3) * 8;

    for (int k0 = 0; k0 < K; k0 += 32) {
        __syncthreads();
        #pragma unroll
        for (int half = 0; half < 2; ++half) {
            int r = srow + half * 64;
            const unsigned short* pA = A2 + (long long)(m0 + r) * lda2 + k0 + scol;
            *(uint4*)&Ah[r * 40 + scol] = *(const uint4*)pA;
            if (NPASS == 3)
                *(uint4*)&Al[r * 40 + scol] = *(const uint4*)(pA + aLo);
            int rb = n0 + r;
            uint4 vh = {0u, 0u, 0u, 0u}, vl = {0u, 0u, 0u, 0u};
            if (rb < N) {
                const unsigned short* pB = B2 + (long long)rb * ldb2 + k0 + scol;
                vh = *(const uint4*)pB;
                if (NPASS == 3) vl = *(const uint4*)(pB + bLo);
            }
            *(uint4*)&Bh[r * 40 + scol] = vh;
            if (NPASS == 3) *(uint4*)&Bl[r * 40 + scol] = vl;
        }
        __syncthreads();

        bf16x8 ah[4], bh[4], al[4], bl[4];
        #pragma unroll
        for (int i = 0; i < 4; ++i) {
            int ra = (wm + i * 16 + lr) * 40 + quad * 8;
            int rb = (wn + i * 16 + lr) * 40 + quad * 8;
            ah[i] = *(const bf16x8*)&Ah[ra];
            bh[i] = *(const bf16x8*)&Bh[rb];
            if (NPASS == 3) {
                al[i] = *(const bf16x8*)&Al[ra];
                bl[i] = *(const bf16x8*)&Bl[rb];
            }
        }
        #pragma unroll
        for (int mi = 0; mi < 4; ++mi)
            #pragma unroll
            for (int ni = 0; ni < 4; ++ni) {
                acc[mi][ni] = __builtin_amdgcn_mfma_f32_16x16x32_bf16(
                    ah[mi], bh[ni], acc[mi][ni], 0, 0, 0);
                if (NPASS == 3) {
                    acc[mi][ni] = __builtin_amdgcn_mfma_f32_16x16x32_bf16(
                        al[mi], bh[ni], acc[mi][ni], 0, 0, 0);
                    acc[mi][ni] = __builtin_amdgcn_mfma_f32_16x16x32_bf16(
                        ah[mi], bl[ni], acc[mi][ni], 0, 0, 0);
                }
            }
    }

    // D layout: col = lane&15, row = quad*4 + r
    if (OUT == 0) {
        float* C = (float*)Cv + bb * sCb + hh * sCh;
        #pragma unroll
        for (int mi = 0; mi < 4; ++mi)
            #pragma unroll
            for (int ni = 0; ni < 4; ++ni) {
                int col = n0 + wn + ni * 16 + lr;
                if (col >= N) continue;
                float bv = bias ? bias[col] : 0.f;
                #pragma unroll
                for (int r = 0; r < 4; ++r) {
                    int row = m0 + wm + mi * 16 + quad * 4 + r;
                    float v = alpha * acc[mi][ni][r] + bv;
                    if (res) v += res[(long long)row * ldr + col];
                    C[(long long)row * ldc + col] = v;
                }
            }
    } else if (OUT == 1) {
        unsigned short* C = (unsigned short*)Cv + bb * sCb + hh * sCh;
        #pragma unroll
        for (int mi = 0; mi < 4; ++mi)
            #pragma unroll
            for (int ni = 0; ni < 4; ++ni) {
                int col = n0 + wn + ni * 16 + lr;
                if (col >= N) continue;
                float bv = bias ? bias[col] : 0.f;
                #pragma unroll
                for (int r = 0; r < 4; ++r) {
                    int row = m0 + wm + mi * 16 + quad * 4 + r;
                    float v = alpha * acc[mi][ni][r] + bv;
                    if (res) v += res[(long long)row * ldr + col];
                    unsigned short hi = bf16_rne(v);
                    unsigned short lo = bf16_rne(v - bf16_tof(hi));
                    long long p = (long long)row * ldc + col;
                    C[p] = hi;
                    C[p + cLo] = lo;
                }
            }
    } else {  // OUT == 2
        unsigned short* C = (unsigned short*)Cv;
        #pragma unroll
        for (int mi = 0; mi < 4; ++mi)
            #pragma unroll
            for (int ni = 0; ni < 4; ++ni) {
                int col = n0 + wn + ni * 16 + lr;
                if (col >= N) continue;
                int row0 = m0 + wm + mi * 16 + quad * 4;
                int b = row0 >> 9, seq0 = row0 & 511;
                ushort4 h4, l4;
                unsigned short* hp = (unsigned short*)&h4;
                unsigned short* lp = (unsigned short*)&l4;
                #pragma unroll
                for (int r = 0; r < 4; ++r) {
                    float v = acc[mi][ni][r];
                    unsigned short hi = bf16_rne(v);
                    hp[r] = hi;
                    lp[r] = bf16_rne(v - bf16_tof(hi));
                }
                long long p = b * sCb + (long long)col * ldc + seq0;
                *(ushort4*)&C[p] = h4;
                *(ushort4*)&C[p + cLo] = l4;
            }
    }
}

// ---------------------------------------------------------------------------
// Tiled f32 GEMM (only for the small batched G = Cm @ Bm^T)
// ---------------------------------------------------------------------------
__global__ __launch_bounds__(256) void gemm_f32_k(
    int M, int N, int K,
    const float* __restrict__ A, int lda, long long sAb,
    const float* __restrict__ B, int ldb, long long sBb,
    float* __restrict__ C, int ldc, long long sCb)
{
    __shared__ float As[32][132];
    __shared__ float Bs[32][132];
    const int z = blockIdx.z;
    A += z * sAb; B += z * sBb; C += z * sCb;
    const int n0 = blockIdx.x * 128;
    const int m0 = blockIdx.y * 128;
    const int t  = threadIdx.x;
    const int tx = t & 15, ty = t >> 4;

    float acc[4][16];
    #pragma unroll
    for (int a = 0; a < 4; ++a)
        #pragma unroll
        for (int q = 0; q < 16; ++q) acc[a][q] = 0.f;

    const int ka = (t & 7) << 2;
    const int ra = t >> 3;

    for (int k0 = 0; k0 < K; k0 += 32) {
        __syncthreads();
        #pragma unroll
        for (int i = 0; i < 4; ++i) {
            int row = m0 + ra + i * 32;
            float4 v = *(const float4*)(A + (long long)row * lda + (k0 + ka));
            As[ka + 0][ra + i * 32] = v.x;
            As[ka + 1][ra + i * 32] = v.y;
            As[ka + 2][ra + i * 32] = v.z;
            As[ka + 3][ra + i * 32] = v.w;
            int rowb = n0 + ra + i * 32;
            float4 w = *(const float4*)(B + (long long)rowb * ldb + (k0 + ka));
            Bs[ka + 0][ra + i * 32] = w.x;
            Bs[ka + 1][ra + i * 32] = w.y;
            Bs[ka + 2][ra + i * 32] = w.z;
            Bs[ka + 3][ra + i * 32] = w.w;
        }
        __syncthreads();
        #pragma unroll
        for (int kk = 0; kk < 32; ++kk) {
            float a[8], bm[8];
            *(float4*)&a[0]  = *(const float4*)&As[kk][ty * 4];
            *(float4*)&a[4]  = *(const float4*)&As[kk][64 + ty * 4];
            *(float4*)&bm[0] = *(const float4*)&Bs[kk][tx * 4];
            *(float4*)&bm[4] = *(const float4*)&Bs[kk][64 + tx * 4];
            #pragma unroll
            for (int ri = 0; ri < 2; ++ri)
                #pragma unroll
                for (int ci = 0; ci < 2; ++ci)
                    #pragma unroll
                    for (int i = 0; i < 4; ++i)
                        #pragma unroll
                        for (int j = 0; j < 4; ++j)
                            acc[ri * 2 + ci][i * 4 + j] =
                                fmaf(a[ri * 4 + i], bm[ci * 4 + j], acc[ri * 2 + ci][i * 4 + j]);
        }
    }
    #pragma unroll
    for (int ri = 0; ri < 2; ++ri)
        #pragma unroll
        for (int ci = 0; ci < 2; ++ci) {
            int colb = n0 + ci * 64 + tx * 4;
            #pragma unroll
            for (int i = 0; i < 4; ++i) {
                int row = m0 + ri * 64 + ty * 4 + i;
                *(float4*)(C + (long long)row * ldc + colb) =
                    *(float4*)&acc[ri * 2 + ci][i * 4];
            }
        }
}

// ---------------------------------------------------------------------------
// Elementwise / norm kernels
// ---------------------------------------------------------------------------
__global__ __launch_bounds__(256) void pairify_k(
    const float* __restrict__ src, unsigned short* __restrict__ dst,
    int k_log2, long long n)
{
    long long idx = (long long)blockIdx.x * 256 + threadIdx.x;
    if (idx >= n) return;
    long long r = idx >> k_log2;
    int c = (int)(idx & ((1 << k_log2) - 1));
    store_pair(dst, r, 1 << k_log2, c, src[idx]);
}

__global__ __launch_bounds__(256) void layernorm_k(
    const float* __restrict__ in, float* __restrict__ out,
    const float* __restrict__ w, const float* __restrict__ b,
    int width, int rows_per_b, long long in_bstride)
{
    long long r = blockIdx.x;
    const float* x = in + (r / rows_per_b) * in_bstride + (r % rows_per_b) * (long long)width;
    int t = threadIdx.x;
    float s = 0.f;
    for (int c = t; c < width; c += 256) s += x[c];
    s = block_sum256(s);
    float m = s / (float)width;
    float vs = 0.f;
    for (int c = t; c < width; c += 256) { float d = x[c] - m; vs += d * d; }
    vs = block_sum256(vs);
    float rs = 1.f / sqrtf(vs / (float)width + 1e-5f);
    float* o = out + r * (long long)width;
    for (int c = t; c < width; c += 256) o[c] = (x[c] - m) * rs * w[c] + b[c];
}

__global__ __launch_bounds__(256) void layernorm_pair_k(
    const float* __restrict__ in, unsigned short* __restrict__ out2,
    const float* __restrict__ w, const float* __restrict__ b,
    int width, int rows_per_b, long long in_bstride)
{
    long long r = blockIdx.x;
    const float* x = in + (r / rows_per_b) * in_bstride + (r % rows_per_b) * (long long)width;
    int t = threadIdx.x;
    float s = 0.f;
    for (int c = t; c < width; c += 256) s += x[c];
    s = block_sum256(s);
    float m = s / (float)width;
    float vs = 0.f;
    for (int c = t; c < width; c += 256) { float d = x[c] - m; vs += d * d; }
    vs = block_sum256(vs);
    float rs = 1.f / sqrtf(vs / (float)width + 1e-5f);
    for (int c = t; c < width; c += 256)
        store_pair(out2, r, width, c, (x[c] - m) * rs * w[c] + b[c]);
}

__global__ __launch_bounds__(256) void rmsnorm_pair_k(
    const float* __restrict__ in, unsigned short* __restrict__ out2,
    const float* __restrict__ w, int width)
{
    long long r = blockIdx.x;
    const float* x = in + r * (long long)width;
    int t = threadIdx.x;
    float s = 0.f;
    for (int c = t; c < width; c += 256) { float v = x[c]; s += v * v; }
    s = block_sum256(s);
    float rs = 1.f / sqrtf(s / (float)width + 1e-5f);
    for (int c = t; c < width; c += 256)
        store_pair(out2, r, width, c, x[c] * rs * w[c]);
}

// Softmax over 512-wide rows, f32 in -> split-pair out IN-PLACE (same bytes).
__global__ __launch_bounds__(256) void softmax_pair_k(float* __restrict__ S,
                                                      unsigned short* __restrict__ P2)
{
    long long r = blockIdx.x;
    float* x = S + r * 512;
    unsigned short* p = P2 + r * 1024;
    int t = threadIdx.x;
    float v0 = x[t], v1 = x[t + 256];
    float mx = block_max256(fmaxf(v0, v1));
    v0 = expf(v0 - mx); v1 = expf(v1 - mx);
    float sum = block_sum256(v0 + v1);
    float inv = 1.f / sum;
    v0 *= inv; v1 *= inv;
    __syncthreads();   // all reads of x complete before pair writes
    unsigned short h0 = bf16_rne(v0);
    p[t] = h0;       p[512 + t] = bf16_rne(v0 - bf16_tof(h0));
    unsigned short h1 = bf16_rne(v1);
    p[t + 256] = h1; p[512 + t + 256] = bf16_rne(v1 - bf16_tof(h1));
}

// Causal grouped conv -> split-pair XC2 (row width 2048)
__global__ __launch_bounds__(256) void conv_k(
    const float* __restrict__ XS, const float* __restrict__ W,
    unsigned short* __restrict__ XC2)
{
    int idx = blockIdx.x * 256 + threadIdx.x;
    int o = idx & 2047;
    int tt = (idx >> 11) & 511;
    int b = idx >> 20;
    int g2 = (o >> 1) << 1;
    const float* Wo = W + o * 8;
    float acc = 0.f;
    #pragma unroll
    for (int k = 0; k < 4; ++k) {
        int ts = tt + k - 3;
        if (ts >= 0) {
            const float* xr = XS + ((long long)(b * 512 + ts)) * 2048;
            acc = fmaf(Wo[k], xr[g2], acc);
            acc = fmaf(Wo[4 + k], xr[g2 + 1], acc);
        }
    }
    store_pair(XC2, (long long)(b * 512 + tt), 2048, o, acc);
}

__global__ __launch_bounds__(256) void dt_k(
    const float* __restrict__ dtBC, const float* __restrict__ dt_bias, float* __restrict__ DT)
{
    int idx = blockIdx.x * 256 + threadIdx.x;
    int r = idx >> 4, h = idx & 15;
    float xv = dtBC[r * 144 + h] + dt_bias[h];
    DT[idx] = (xv > 20.f) ? xv : log1pf(expf(xv));
}

__global__ __launch_bounds__(64) void cuma_k(
    const float* __restrict__ DT, const float* __restrict__ A_log, float* __restrict__ CUMA)
{
    int h = blockIdx.x, b = blockIdx.y;
    int ln = threadIdx.x;
    float Ah = -expf(A_log[h]);
    float v[8];
    float run = 0.f;
    #pragma unroll
    for (int i = 0; i < 8; ++i) {
        run += Ah * DT[((b * 512) + (ln * 8 + i)) * 16 + h];
        v[i] = run;
    }
    float tot = run;
    float sc = tot;
    #pragma unroll
    for (int o = 1; o <= 32; o <<= 1) {
        float u = __shfl_up(sc, o, 64);
        if (ln >= o) sc += u;
    }
    float excl = sc - tot;
    #pragma unroll
    for (int i = 0; i < 8; ++i)
        CUMA[(b * 16 + h) * 512 + ln * 8 + i] = excl + v[i];
}

// SSD apply + D-skip + silu(z) gate. XC read from split pairs; out split pairs.
__global__ __launch_bounds__(256) void ssd_apply_k(
    const float* __restrict__ G, const float* __restrict__ CUMA,
    const float* __restrict__ DT, const unsigned short* __restrict__ XC2,
    const float* __restrict__ Z, const float* __restrict__ Dv,
    unsigned short* __restrict__ YS2)
{
    int lt = blockIdx.x, h = blockIdx.y, b = blockIdx.z;
    int t = threadIdx.x;
    int p = t & 127, lg = t >> 7;
    int li = t >> 4, si = t & 15;
    __shared__ float XCs[16][128];
    __shared__ float Ws[16][16];
    float acc[8];
    #pragma unroll
    for (int r = 0; r < 8; ++r) acc[r] = 0.f;

    int lglob = lt * 16 + li;
    float cAl = CUMA[(b * 16 + h) * 512 + lglob];

    for (int st = 0; st <= lt; ++st) {
        __syncthreads();
        #pragma unroll
        for (int j = 0; j < 8; ++j) {
            int idx = t + j * 256;
            int sr = idx >> 7, sc = idx & 127;
            long long q = ((long long)(b * 512 + st * 16 + sr)) * 4096 + h * 128 + sc;
            XCs[sr][sc] = bf16_tof(XC2[q]) + bf16_tof(XC2[q + 2048]);
        }
        int sglob = st * 16 + si;
        float wv = 0.f;
        if (sglob <= lglob) {
            float cAs = CUMA[(b * 16 + h) * 512 + sglob];
            wv = G[((long long)(b * 512 + lglob)) * 512 + sglob] * expf(cAl - cAs)
                 * DT[(b * 512 + sglob) * 16 + h];
        }
        Ws[li][si] = wv;
        __syncthreads();
        #pragma unroll
        for (int ss = 0; ss < 16; ++ss) {
            float xv = XCs[ss][p];
            #pragma unroll
            for (int r = 0; r < 8; ++r)
                acc[r] = fmaf(Ws[lg + r * 2][ss], xv, acc[r]);
        }
    }
    float Dh = Dv[h];
    #pragma unroll
    for (int r = 0; r < 8; ++r) {
        int l = lt * 16 + lg + r * 2;
        long long row = (long long)(b * 512 + l);
        long long q = row * 4096 + h * 128 + p;
        float xc = bf16_tof(XC2[q]) + bf16_tof(XC2[q + 2048]);
        float zz = Z[row * 2048 + h * 128 + p];
        float sil = zz / (1.f + expf(-zz));
        store_pair(YS2, row, 2048, h * 128 + p, (acc[r] + xc * Dh) * sil);
    }
}

// hc = LayerNorm64(G1) -> {-1,+1} as split pairs (lo = 0)
__global__ __launch_bounds__(64) void hc_quant_k(
    const float* __restrict__ G1, const float* __restrict__ w,
    const float* __restrict__ b, unsigned short* __restrict__ HCQ2)
{
    int r = blockIdx.x, ln = threadIdx.x;
    float v = G1[r * 64 + ln];
    float s = v;
    #pragma unroll
    for (int o = 32; o > 0; o >>= 1) s += __shfl_xor(s, o, 64);
    float m = s * (1.f / 64.f);
    float d = v - m;
    float vs = d * d;
    #pragma unroll
    for (int o = 32; o > 0; o >>= 1) vs += __shfl_xor(vs, o, 64);
    vs *= (1.f / 64.f);
    float hc = d * (1.f / sqrtf(vs + 1e-5f)) * w[ln] + b[ln];
    HCQ2[r * 128 + ln] = (hc > 0.f) ? 0x3F80 : 0xBF80;
    HCQ2[r * 128 + 64 + ln] = 0;
}

__global__ __launch_bounds__(256) void dxm_k(
    const float* __restrict__ mtok, const float* __restrict__ e2d, float* __restrict__ dxm)
{
    int c = blockIdx.x * 256 + threadIdx.x;
    float acc = 0.f;
    #pragma unroll
    for (int j = 0; j < 64; ++j) acc = fmaf(mtok[j], e2d[c * 64 + j], acc);
    dxm[c] = acc;
}

__global__ __launch_bounds__(256) void projm_k(
    const float* __restrict__ lnm,
    const float* __restrict__ bWq, const float* __restrict__ bWk, const float* __restrict__ bWv,
    float* __restrict__ qm, float* __restrict__ km, float* __restrict__ vm)
{
    int idx = blockIdx.x * 256 + threadIdx.x;
    int sel = idx >> 10, c = idx & 1023;
    const float* W = (sel == 0) ? bWq : (sel == 1) ? bWk : bWv;
    float* O = (sel == 0) ? qm : (sel == 1) ? km : vm;
    const float* wr = W + (long long)c * 1024;
    float acc = 0.f;
    for (int j = 0; j < 1024; j += 4) {
        float4 a = *(const float4*)(lnm + j);
        float4 w4 = *(const float4*)(wr + j);
        acc = fmaf(a.x, w4.x, fmaf(a.y, w4.y, fmaf(a.z, w4.z, fmaf(a.w, w4.w, acc))));
    }
    O[c] = acc;
}

// Collapsed decoder attention: 1 query/(b,h); keys = 512 visible + mask key x512.
__global__ __launch_bounds__(256) void dec_attn_k(
    const float* __restrict__ Kv, const float* __restrict__ Vv,
    const float* __restrict__ qm, const float* __restrict__ km,
    const float* __restrict__ vm, float* __restrict__ OBm)
{
    int h = blockIdx.x, b = blockIdx.y;
    int t = threadIdx.x;
    __shared__ __align__(16) float qs[256];
    __shared__ __align__(16) float ps[512];
    qs[t] = qm[h * 256 + t];
    __syncthreads();
    float s[2];
    #pragma unroll
    for (int i = 0; i < 2; ++i) {
        int r = t + i * 256;
        const float* kr = Kv + ((long long)(b * 512 + r)) * 1024 + h * 256;
        float acc = 0.f;
        for (int c = 0; c < 256; c += 4) {
            float4 k4 = *(const float4*)(kr + c);
            float4 q4 = *(const float4*)(qs + c);
            acc = fmaf(k4.x, q4.x, fmaf(k4.y, q4.y, fmaf(k4.z, q4.z, fmaf(k4.w, q4.w, acc))));
        }
        s[i] = acc * (1.f / 16.f);
    }
    float accm = 0.f;
    for (int c = 0; c < 256; c += 4) {
        float4 k4 = *(const float4*)(km + h * 256 + c);
        float4 q4 = *(const float4*)(qs + c);
        accm = fmaf(k4.x, q4.x, fmaf(k4.y, q4.y, fmaf(k4.z, q4.z, fmaf(k4.w, q4.w, accm))));
    }
    float smv = accm * (1.f / 16.f);
    float mx = block_max256(fmaxf(fmaxf(s[0], s[1]), smv));
    float p0 = expf(s[0] - mx), p1 = expf(s[1] - mx);
    ps[t] = p0; ps[t + 256] = p1;
    float pm = expf(smv - mx) * 512.f;
    float sum = block_sum256(p0 + p1) + pm;
    float inv = 1.f / sum;
    __syncthreads();
    float o = pm * vm[h * 256 + t];
    const float* vcol = Vv + (long long)b * 512 * 1024 + h * 256 + t;
    for (int j = 0; j < 512; ++j)
        o = fmaf(ps[j], vcol[(long long)j * 1024], o);
    OBm[b * 1024 + h * 256 + t] = o * inv;
}

__global__ __launch_bounds__(256) void ydm_k(
    const float* __restrict__ OBm, const float* __restrict__ bWo,
    const float* __restrict__ bWo_b, const float* __restrict__ dxm,
    float* __restrict__ ydm)
{
    int idx = blockIdx.x * 256 + threadIdx.x;
    int b = idx >> 10, c = idx & 1023;
    const float* ar = OBm + b * 1024;
    const float* wr = bWo + (long long)c * 1024;
    float acc = 0.f;
    for (int j = 0; j < 1024; j += 4) {
        float4 a = *(const float4*)(ar + j);
        float4 w4 = *(const float4*)(wr + j);
        acc = fmaf(a.x, w4.x, fmaf(a.y, w4.y, fmaf(a.z, w4.z, fmaf(a.w, w4.w, acc))));
    }
    ydm[idx] = acc + bWo_b[c] + dxm[c];
}

__global__ __launch_bounds__(256) void outm_k(
    const float* __restrict__ ydm, const float* __restrict__ dout_W,
    const float* __restrict__ dout_b, float* __restrict__ outm)
{
    int idx = blockIdx.x * 256 + threadIdx.x;
    int b = idx >> 11, c = idx & 2047;
    const float* ar = ydm + b * 1024;
    const float* wr = dout_W + (long long)c * 1024;
    float acc = 0.f;
    for (int j = 0; j < 1024; j += 4) {
        float4 a = *(const float4*)(ar + j);
        float4 w4 = *(const float4*)(wr + j);
        acc = fmaf(a.x, w4.x, fmaf(a.y, w4.y, fmaf(a.z, w4.z, fmaf(a.w, w4.w, acc))));
    }
    outm[idx] = acc + dout_b[c];
}

__global__ __launch_bounds__(256) void bcast_k(
    const float* __restrict__ outm, float* __restrict__ out)
{
    int idx = blockIdx.x * 256 + threadIdx.x;
    int c4 = idx & 511;
    int b = idx >> 18;
    ((float4*)out)[idx] = ((const float4*)outm)[b * 512 + c4];
}

// ---------------------------------------------------------------------------
// Host-side launcher
// ---------------------------------------------------------------------------
static inline void pairify(hipStream_t s, const float* src, unsigned short* dst,
                           int k_log2, long long n)
{
    pairify_k<<<(int)((n + 255) / 256), 256, 0, s>>>(src, dst, k_log2, n);
}

extern "C" void kernel_launch(void* const* d_in, const int* in_sizes, int n_in,
                              void* d_out, int out_size, void* d_ws, size_t ws_size,
                              hipStream_t stream)
{
    const float* x       = (const float*)d_in[0];
    const float* ln0_w   = (const float*)d_in[1];
    const float* ln0_b   = (const float*)d_in[2];
    const float* in_W    = (const float*)d_in[3];
    const float* rms_w   = (const float*)d_in[4];
    const float* exp_W   = (const float*)d_in[5];
    const float* conv_W  = (const float*)d_in[6];
    const float* xproj_W = (const float*)d_in[7];
    const float* dt_bias = (const float*)d_in[8];
    const float* A_log   = (const float*)d_in[9];
    const float* Dv      = (const float*)d_in[10];
    const float* outp_W  = (const float*)d_in[11];
    const float* outp_b  = (const float*)d_in[12];
    const float* n1_w    = (const float*)d_in[13];
    const float* n1_b    = (const float*)d_in[14];
    const float* aWq     = (const float*)d_in[15];
    const float* aWk     = (const float*)d_in[16];
    const float* aWv     = (const float*)d_in[17];
    const float* aWo     = (const float*)d_in[18];
    const float* aWo_b   = (const float*)d_in[19];
    const float* h_W     = (const float*)d_in[20];
    const float* h_b     = (const float*)d_in[21];
    const float* h_lnw   = (const float*)d_in[22];
    const float* h_lnb   = (const float*)d_in[23];
    const float* mtok    = (const float*)d_in[24];
    const float* e2d_W   = (const float*)d_in[25];
    const float* dn_w    = (const float*)d_in[26];
    const float* dn_b    = (const float*)d_in[27];
    const float* bWq     = (const float*)d_in[28];
    const float* bWk     = (const float*)d_in[29];
    const float* bWv     = (const float*)d_in[30];
    const float* bWo     = (const float*)d_in[31];
    const float* bWo_b   = (const float*)d_in[32];
    const float* dout_W  = (const float*)d_in[33];
    const float* dout_b  = (const float*)d_in[34];

    float* ws  = (float*)d_ws;
    float* out = (float*)d_out;

    // ---- slots (float offsets); total ~220 MiB ----
    float* S1 = ws;              // 8.39M: XV2 | exp_W2 | SA/P2 | Kv+Vv
    float* S2 = ws + 8388608;    // 8.39M: in_W2 | XS | YS2
    float* S3 = ws + 16777216;   // 8.39M: XC2 | outp_W2 | DXV + LNDXV2
    float* S4 = ws + 25165824;   // 8.39M: Z | aW{q,k,v,o}2 + bW{k,v}2
    float* S5 = ws + 33554432;   // 4.19M: T | QA2 | Y22
    float* S6 = ws + 37748736;   // 4.19M: HR2 | Y1
    float* S7 = ws + 41943040;   // 4.19M: LNY2 | OA2
    float* S8 = ws + 46137344;   // 4.19M: KA2
    float* S9 = ws + 50331648;   // 4.19M: VT2
    float* SP = ws + 54525952;   // 3.25M small pool

    unsigned short* XV2     = (unsigned short*)S1;
    unsigned short* exp_W2  = (unsigned short*)S1;
    float*          SA      = S1;
    unsigned short* P2      = (unsigned short*)S1;
    float*          Kv      = S1;
    float*          Vv      = S1 + 4194304;
    unsigned short* in_W2   = (unsigned short*)S2;
    float*          XS      = S2;
    unsigned short* YS2     = (unsigned short*)S2;
    unsigned short* XC2     = (unsigned short*)S3;
    unsigned short* outp_W2 = (unsigned short*)S3;
    float*          DXV     = S3;
    unsigned short* LNDXV2  = (unsigned short*)(S3 + 4194304);
    float*          Z       = S4;
    unsigned short* aWq2    = (unsigned short*)S4;
    unsigned short* aWk2    = (unsigned short*)S4 + 2097152;
    unsigned short* aWv2    = (unsigned short*)S4 + 4194304;
    unsigned short* aWo2    = (unsigned short*)S4 + 6291456;
    unsigned short* bWk2    = (unsigned short*)S4 + 8388608;
    unsigned short* bWv2    = (unsigned short*)S4 + 10485760;
    float*          T       = S5;
    unsigned short* QA2     = (unsigned short*)S5;
    unsigned short* Y22     = (unsigned short*)S5;
    unsigned short* HR2     = (unsigned short*)S6;
    float*          Y1      = S6;
    unsigned short* LNY2    = (unsigned short*)S7;
    unsigned short* OA2     = (unsigned short*)S7;
    unsigned short* KA2     = (unsigned short*)S8;
    unsigned short* VT2     = (unsigned short*)S9;

    float* dtBC = SP;                     // 589,824
    float* DT   = SP + 589824;            // 65,536
    float* CUMA = SP + 655360;            // 65,536
    float* G    = SP + 720896;            // 2,097,152  [live steps 7-8]
    unsigned short* xprojW2 = (unsigned short*)(SP + 2818048);  // 294,912 fl
    unsigned short* hW2     = (unsigned short*)(SP + 3112960);  // 65,536 fl
    unsigned short* e2dW2   = (unsigned short*)(SP + 3178496);  // 65,536 fl
    float* G1   = SP + 720896;            // alias over dead G
    unsigned short* HCQ2 = (unsigned short*)(SP + 983040);      // 262,144 fl
    float* dxm  = SP + 1245184;
    float* lnm  = SP + 1246208;
    float* qm   = SP + 1247232;
    float* km   = SP + 1248256;
    float* vm   = SP + 1249280;
    float* OBm  = SP + 1250304;
    float* ydm  = SP + 1258496;
    float* outm = SP + 1266688;

    const long long LL0 = 0;
    #define G3(OUTM, GX, GY, GZ, ...) \
        gemm_bf16_k<3, OUTM><<<dim3(GX, GY, GZ), 256, 0, stream>>>(__VA_ARGS__)
    #define G1P(OUTM, GX, GY, GZ, ...) \
        gemm_bf16_k<1, OUTM><<<dim3(GX, GY, GZ), 256, 0, stream>>>(__VA_ARGS__)

    // ---- weight prep (phase A) ----
    pairify(stream, in_W,    in_W2,   11, 1024LL * 2048);
    pairify(stream, xproj_W, xprojW2, 11, 144LL * 2048);
    pairify(stream, h_W,     hW2,     10, 64LL * 1024);
    pairify(stream, e2d_W,   e2dW2,    6, 1024LL * 64);

    // ---- encoder trunk ----
    layernorm_pair_k<<<4096, 256, 0, stream>>>(x, XV2, ln0_w, ln0_b, 2048, 512,
                                               (long long)1024 * 2048);
    G3(0, 8, 32, 1, 4096, 1024, 2048, XV2, 4096, 2048, LL0, LL0,
       in_W2, 4096, 2048, LL0, LL0, T, 1024, 0, LL0, LL0,
       nullptr, nullptr, 0, 1.f, 1);
    pairify(stream, exp_W, exp_W2, 10, 4096LL * 1024);   // S1 (XV2 dead)
    rmsnorm_pair_k<<<4096, 256, 0, stream>>>(T, HR2, rms_w, 1024);
    G3(0, 16, 32, 1, 4096, 2048, 1024, HR2, 2048, 1024, LL0, LL0,
       exp_W2, 2048, 1024, LL0, LL0, XS, 2048, 0, LL0, LL0,
       nullptr, nullptr, 0, 1.f, 1);
    G3(0, 16, 32, 1, 4096, 2048, 1024, HR2, 2048, 1024, LL0, LL0,
       exp_W2 + 2048LL * 2048, 2048, 1024, LL0, LL0, Z, 2048, 0, LL0, LL0,
       nullptr, nullptr, 0, 1.f, 1);
    conv_k<<<32768, 256, 0, stream>>>(XS, conv_W, XC2);
    G3(0, 2, 32, 1, 4096, 144, 2048, XC2, 4096, 2048, LL0, LL0,
       xprojW2, 4096, 2048, LL0, LL0, dtBC, 144, 0, LL0, LL0,
       nullptr, nullptr, 0, 1.f, 1);
    dt_k<<<256, 256, 0, stream>>>(dtBC, dt_bias, DT);
    cuma_k<<<dim3(16, 8), 64, 0, stream>>>(DT, A_log, CUMA);
    gemm_f32_k<<<dim3(4, 4, 8), 256, 0, stream>>>(
        512, 512, 64, dtBC + 80, 144, (long long)512 * 144,
        dtBC + 16, 144, (long long)512 * 144, G, 512, (long long)512 * 512);
    ssd_apply_k<<<dim3(32, 16, 8), 256, 0, stream>>>(G, CUMA, DT, XC2, Z, Dv, YS2);

    // ---- weight prep (phase B: S3/S4 now dead) ----
    pairify(stream, outp_W, outp_W2, 11, 1024LL * 2048);
    pairify(stream, aWq, aWq2, 10, 1024LL * 1024);
    pairify(stream, aWk, aWk2, 10, 1024LL * 1024);
    pairify(stream, aWv, aWv2, 10, 1024LL * 1024);
    pairify(stream, aWo, aWo2, 10, 1024LL * 1024);
    pairify(stream, bWk, bWk2, 10, 1024LL * 1024);
    pairify(stream, bWv, bWv2, 10, 1024LL * 1024);

    G3(0, 8, 32, 1, 4096, 1024, 2048, YS2, 4096, 2048, LL0, LL0,
       outp_W2, 4096, 2048, LL0, LL0, Y1, 1024, 0, LL0, LL0,
       outp_b, T, 1024, 1.f, 1);

    // ---- encoder attention (all MFMA) ----
    layernorm_pair_k<<<4096, 256, 0, stream>>>(Y1, LNY2, n1_w, n1_b, 1024, 4096, LL0);
    G3(1, 8, 32, 1, 4096, 1024, 1024, LNY2, 2048, 1024, LL0, LL0,
       aWq2, 2048, 1024, LL0, LL0, QA2, 2048, 1024, LL0, LL0,
       nullptr, nullptr, 0, 1.f, 1);
    G3(1, 8, 32, 1, 4096, 1024, 1024, LNY2, 2048, 1024, LL0, LL0,
       aWk2, 2048, 1024, LL0, LL0, KA2, 2048, 1024, LL0, LL0,
       nullptr, nullptr, 0, 1.f, 1);
    G3(2, 8, 32, 1, 4096, 1024, 1024, LNY2, 2048, 1024, LL0, LL0,
       aWv2, 2048, 1024, LL0, LL0, VT2, 1024, 512, (long long)1024 * 1024, LL0,
       nullptr, nullptr, 0, 1.f, 1);
    // scores: z=(b*4+h); A/B head-offset in k; C f32 per-z
    G3(0, 4, 4, 32, 512, 512, 256,
       QA2, 2048, 1024, (long long)512 * 2048, 256,
       KA2, 2048, 1024, (long long)512 * 2048, 256,
       SA, 512, 0, (long long)4 * 512 * 512, (long long)512 * 512,
       nullptr, nullptr, 0, 1.f / 16.f, 4);
    softmax_pair_k<<<16384, 256, 0, stream>>>(SA, P2);
    // PV: A=P2, B=VT2 (chan-major), C=OA2 pairs
    G3(1, 2, 4, 32, 512, 256, 512,
       P2, 1024, 512, (long long)4 * 512 * 1024, (long long)512 * 1024,
       VT2, 1024, 512, (long long)1024 * 1024, (long long)256 * 1024,
       OA2, 2048, 1024, (long long)512 * 2048, 256,
       nullptr, nullptr, 0, 1.f, 4);
    G3(1, 8, 32, 1, 4096, 1024, 1024, OA2, 2048, 1024, LL0, LL0,
       aWo2, 2048, 1024, LL0, LL0, Y22, 2048, 1024, LL0, LL0,
       aWo_b, Y1, 1024, 1.f, 1);

    // ---- quantize ----
    G3(0, 1, 32, 1, 4096, 64, 1024, Y22, 2048, 1024, LL0, LL0,
       hW2, 2048, 1024, LL0, LL0, G1, 64, 0, LL0, LL0,
       h_b, nullptr, 0, 1.f, 1);
    hc_quant_k<<<4096, 64, 0, stream>>>(G1, h_lnw, h_lnb, HCQ2);

    // ---- decoder (collapsed masked rows) ----
    G3(0, 8, 32, 1, 4096, 1024, 64, HCQ2, 128, 64, LL0, LL0,
       e2dW2, 128, 64, LL0, LL0, DXV, 1024, 0, LL0, LL0,
       nullptr, nullptr, 0, 1.f, 1);
    dxm_k<<<4, 256, 0, stream>>>(mtok, e2d_W, dxm);
    layernorm_k<<<1, 256, 0, stream>>>(dxm, lnm, dn_w, dn_b, 1024, 1, LL0);
    layernorm_pair_k<<<4096, 256, 0, stream>>>(DXV, LNDXV2, dn_w, dn_b, 1024, 4096, LL0);
    projm_k<<<12, 256, 0, stream>>>(lnm, bWq, bWk, bWv, qm, km, vm);
    G1P(0, 8, 32, 1, 4096, 1024, 1024, LNDXV2, 2048, 1024, LL0, LL0,
        bWk2, 2048, 1024, LL0, LL0, Kv, 1024, 0, LL0, LL0,
        nullptr, nullptr, 0, 1.f, 1);
    G1P(0, 8, 32, 1, 4096, 1024, 1024, LNDXV2, 2048, 1024, LL0, LL0,
        bWv2, 2048, 1024, LL0, LL0, Vv, 1024, 0, LL0, LL0,
        nullptr, nullptr, 0, 1.f, 1);
    dec_attn_k<<<dim3(4, 8), 256, 0, stream>>>(Kv, Vv, qm, km, vm, OBm);
    ydm_k<<<32, 256, 0, stream>>>(OBm, bWo, bWo_b, dxm, ydm);
    outm_k<<<64, 256, 0, stream>>>(ydm, dout_W, dout_b, outm);
    bcast_k<<<8192, 256, 0, stream>>>(outm, out);
    #undef G3
    #undef G1P
}